// Round 9
// baseline (502.975 us; speedup 1.0000x reference)
//
#include <hip/hip_runtime.h>
#include <hip/hip_bf16.h>
#include <stdint.h>

typedef unsigned int uint_t;
typedef unsigned short ushort_t;

#define NN 100000
#define EE 1600000
#define CC 25000
#define DINTER 144
#define NBKT 196          // C-side coarse buckets: src cluster >> 7
#define NBKT2 1568        // A-side buckets: (src_node/12500)*196 + (dst_node>>9)
#define NSEG 6272         // dedupe segments: 196 buckets * 32 subs (4 u-clusters each)
#define KCAP 1024         // keys per segment cap (mean 256, sigma 16 -> +48 sigma)

// ---- ws layout in 32-bit words (total 92.27 MB, proven) ----
#define W_M1B      0u         // u16 [131*128] bf16 m1 = 8384 words
#define W_AGGB     8384u      // bf16[25000*132] = 1,650,000 words (pkW alias pre-agg_merge)
#define W_PAGG     1658384u   // bf16[8][25000*132] = 13,200,000 words (kbuf reuse after agg_merge)
#define W_PKA4     14858384u  // uint4[1,600,000] = 6,400,000 words (csub/bcnt/ebase reuse after sort)
#define W_PKC      21258384u  // u32 [1600000]
#define W_OFFS2    22858384u  // u32 [200001]  per-(slice,cluster) segment offsets
#define W_BHA2     23058385u  // u32 [1568]
#define W_BHC      23059953u  // u32 [196]   (adjacent to BHA2: one memset of 1764)
#define W_BBA2     23060149u  // u32 [1569]
#define W_BCURA2   23061718u  // u32 [1568]
#define W_BBC      23063286u  // u32 [197]
#define W_BCURC    23063483u  // u32 [196]
#define WS_WORDS   23066816u

// ---- out layout in FLOAT32 elements (total 11,300,000) ----
#define O_XNEW  0u
#define O_POS   3200000u
#define O_EI    3275000u
#define O_ATTR  6475000u
#define O_BATCH 11275000u
// x_bf16 staging: first 6.4M words of the O_EI region (re-zeroed before enc_count/emit)
// new_pos f32[25000*3] lives at out[O_POS] and is read back by enc_emit.

static __device__ __forceinline__ uint_t f2bf(float f) {
    union { float f; uint_t i; } v; v.f = f;
    uint_t x = v.i;
    return (x + 0x7fffu + ((x >> 16) & 1u)) >> 16;  // RNE
}
static __device__ __forceinline__ float bf2f(ushort_t u) {
    union { uint_t i; float f; } v; v.i = ((uint_t)u) << 16; return v.f;
}

// K0: pack x (f32) -> bf16x2 words into the output-staging region.
__global__ void xpack(const float4* __restrict__ x4, uint2* __restrict__ xb2) {
    int i = blockIdx.x * 256 + threadIdx.x;
    if (i >= NN * 32) return;            // 12.8M floats / 4
    float4 v = x4[i];
    uint2 r;
    r.x = f2bf(v.x) | (f2bf(v.y) << 16);
    r.y = f2bf(v.z) | (f2bf(v.w) << 16);
    xb2[i] = r;
}

// K1: M1[j][o] = sum_f Wrow_j[f] * Wg[f][o], emitted directly as bf16.
__global__ void build_m1f(const float* __restrict__ Wconv,
                          const float* __restrict__ Wedge,
                          const float* __restrict__ Wg,
                          ushort_t* __restrict__ m1b) {
    int j = blockIdx.x;   // 0..130
    int o = threadIdx.x;  // 0..127
    const float* wrow = (j < 128) ? (Wconv + j * DINTER + 16)
                                  : (Wedge + (j - 128) * DINTER + 16);
    float acc = 0.f;
    for (int f = 0; f < 128; ++f)
        acc += wrow[f] * Wg[f * 128 + o];
    m1b[j * 128 + o] = (ushort_t)f2bf(acc);
}

// K2a: fused coarse histograms (LDS-aggregated).
// hA2: (src_slice, dst_node >> 9).  hC: src cluster >> 7 (dedupe).
__global__ void edge_hist2(const int* __restrict__ ei,
                           uint_t* __restrict__ bhA2, uint_t* __restrict__ bhC) {
    __shared__ uint_t hA[NBKT2], hC[NBKT];
    int tid = threadIdx.x;
    for (int i = tid; i < NBKT2; i += 256) hA[i] = 0;
    for (int i = tid; i < NBKT; i += 256) hC[i] = 0;
    __syncthreads();
    for (int e = blockIdx.x * 256 + tid; e < EE; e += 256 * 256) {
        uint_t u = (uint_t)ei[e];
        uint_t v = (uint_t)ei[EE + e];
        atomicAdd(&hA[(u / 12500u) * 196u + (v >> 9)], 1u);
        atomicAdd(&hC[u >> 9], 1u);
    }
    __syncthreads();
    for (int i = tid; i < NBKT2; i += 256) if (hA[i]) atomicAdd(&bhA2[i], hA[i]);
    for (int i = tid; i < NBKT; i += 256)  if (hC[i]) atomicAdd(&bhC[i], hC[i]);
}

// Single-block exclusive scan. out[0..n] (out[n]=total), optional copy out2[0..n-1].
__global__ void scan_small(const uint_t* __restrict__ in, uint_t* __restrict__ out,
                           uint_t* __restrict__ out2, int n) {
    __shared__ uint_t part[256];
    int tid = threadIdx.x;
    int per = (n + 255) >> 8;
    int lo = tid * per;
    int hi = lo + per; if (hi > n) hi = n;
    if (lo > n) lo = n;
    uint_t s = 0;
    for (int i = lo; i < hi; ++i) s += in[i];
    part[tid] = s;
    __syncthreads();
    for (int off = 1; off < 256; off <<= 1) {
        uint_t v = (tid >= off) ? part[tid - off] : 0u;
        __syncthreads();
        part[tid] += v;
        __syncthreads();
    }
    uint_t run = part[tid] - s;
    for (int i = lo; i < hi; ++i) {
        out[i] = run;
        if (out2) out2[i] = run;
        run += in[i];
    }
    if (tid == 255) out[n] = run;
}

#define TPB 4096
// K2b: bucket scatter for the reduce. Payload uint4 = {(cl<<17)|src, ea.x, ea.y, ea.z}
// so downstream never gathers ei[] or ea[] (both read COALESCED here).
__global__ void bucket_place_A2(const int* __restrict__ ei, const float* __restrict__ ea,
                                uint_t* __restrict__ bcur, uint4* __restrict__ pk4) {
    __shared__ uint_t hist[NBKT2], gbase[NBKT2], cur[NBKT2];
    int tid = threadIdx.x;
    int t0 = blockIdx.x * TPB;
    int nt = EE - t0; if (nt > TPB) nt = TPB;
    for (int i = tid; i < NBKT2; i += 256) { hist[i] = 0; cur[i] = 0; }
    __syncthreads();
    for (int i = tid; i < nt; i += 256) {
        int e = t0 + i;
        uint_t u = (uint_t)ei[e];
        uint_t v = (uint_t)ei[EE + e];
        atomicAdd(&hist[(u / 12500u) * 196u + (v >> 9)], 1u);
    }
    __syncthreads();
    for (int b = tid; b < NBKT2; b += 256) {
        uint_t h = hist[b];
        if (h) gbase[b] = atomicAdd(&bcur[b], h);
    }
    __syncthreads();
    for (int i = tid; i < nt; i += 256) {
        int e = t0 + i;
        uint_t u = (uint_t)ei[e];
        uint_t v = (uint_t)ei[EE + e];
        uint_t b = (u / 12500u) * 196u + (v >> 9);
        uint_t r = gbase[b] + atomicAdd(&cur[b], 1u);
        uint4 p;
        p.x = (((v >> 2) & 127u) << 17) | u;
        p.y = __float_as_uint(ea[(size_t)e * 3 + 0]);
        p.z = __float_as_uint(ea[(size_t)e * 3 + 1]);
        p.w = __float_as_uint(ea[(size_t)e * 3 + 2]);
        pk4[r] = p;
    }
}

// K2b': dedupe-side bucket scatter; full key (u<<15)|v fits u32, bucket = pk>>22.
__global__ void bucket_place_C(const int* __restrict__ ei, uint_t* __restrict__ bcur,
                               uint_t* __restrict__ pkC) {
    __shared__ uint_t pk[TPB];
    __shared__ uint_t gpk[TPB];
    __shared__ uint_t hist[NBKT], lbase[NBKT], gbase[NBKT], cur[NBKT];
    __shared__ uint_t part[256];
    int tid = threadIdx.x;
    int t0 = blockIdx.x * TPB;
    int nt = EE - t0; if (nt > TPB) nt = TPB;
    for (int i = tid; i < NBKT; i += 256) { hist[i] = 0; cur[i] = 0; }
    __syncthreads();
    for (int i = tid; i < nt; i += 256) {
        int e = t0 + i;
        uint_t u = ((uint_t)ei[e]) >> 2;
        uint_t v = ((uint_t)ei[EE + e]) >> 2;
        uint_t w = (u << 15) | v;
        pk[i] = w;
        atomicAdd(&hist[w >> 22], 1u);
    }
    __syncthreads();
    uint_t h = (tid < NBKT) ? hist[tid] : 0u;
    if (tid < NBKT) gbase[tid] = atomicAdd(&bcur[tid], h);
    part[tid] = h;
    __syncthreads();
    for (int off = 1; off < 256; off <<= 1) {
        uint_t v = (tid >= off) ? part[tid - off] : 0u;
        __syncthreads();
        part[tid] += v;
        __syncthreads();
    }
    if (tid < NBKT) lbase[tid] = part[tid] - h;
    __syncthreads();
    for (int i = tid; i < nt; i += 256) {
        uint_t b = pk[i] >> 22;
        uint_t r = lbase[b] + atomicAdd(&cur[b], 1u);
        gpk[r] = pk[i];
    }
    __syncthreads();
    for (int r = tid; r < nt; r += 256) {
        uint_t b = gpk[r] >> 22;
        pkC[gbase[b] + ((uint_t)r - lbase[b])] = gpk[r];
    }
}

// K2c: in-LDS counting sort of each (slice, dst-coarse) bucket by cluster-local id;
// sorted KEYS (.x) written to pkW (aliases aggb, dead until agg_merge).
// ea sums per cluster via LDS FLOAT ATOMICS keyed by the cluster id in the key —
// CORRECTNESS FIX for round 8, which wrongly read st[] ranges as if sorted
// (st stays unsorted; only pkW gets sort order) -> absmax blew up 0.25 -> 41.9.
__global__ void bucket_sort_A2(const uint_t* __restrict__ bbA2, const uint4* __restrict__ pk4,
                               uint_t* __restrict__ pkW, uint_t* __restrict__ paggw,
                               uint_t* __restrict__ offs2) {
    __shared__ uint4 st[2048];                      // 32 KB payload staging
    __shared__ uint_t hist[128], base2[128], cur[128];
    __shared__ float eacc0[128], eacc1[128], eacc2[128];
    __shared__ uint_t part[256];
    int tid = threadIdx.x, bk = blockIdx.x;
    uint_t s = bbA2[bk], epos = bbA2[bk + 1];
    int n = (int)(epos - s);
    if (n > 2048) n = 2048;   // statistically unreachable; guards LDS bounds
    if (tid < 128) {
        hist[tid] = 0; cur[tid] = 0;
        eacc0[tid] = 0.f; eacc1[tid] = 0.f; eacc2[tid] = 0.f;
    }
    for (int i = tid; i < n; i += 256) st[i] = pk4[s + i];
    __syncthreads();
    for (int i = tid; i < n; i += 256) {
        uint4 p = st[i];
        uint_t d = p.x >> 17;
        atomicAdd(&hist[d], 1u);
        atomicAdd(&eacc0[d], __uint_as_float(p.y));
        atomicAdd(&eacc1[d], __uint_as_float(p.z));
        atomicAdd(&eacc2[d], __uint_as_float(p.w));
    }
    __syncthreads();
    uint_t h = (tid < 128) ? hist[tid] : 0u;
    part[tid] = h;
    __syncthreads();
    for (int off = 1; off < 256; off <<= 1) {
        uint_t v = (tid >= off) ? part[tid - off] : 0u;
        __syncthreads();
        part[tid] += v;
        __syncthreads();
    }
    int sl = bk / 196, q = bk - sl * 196;
    if (tid < 128) {
        base2[tid] = part[tid] - h;
        int c = q * 128 + tid;
        if (c < CC) {
            uint_t kk = (uint_t)sl * CC + (uint_t)c;
            offs2[kk] = s + base2[tid];
            paggw[(size_t)kk * 66 + 64] = f2bf(eacc0[tid]) | (f2bf(eacc1[tid]) << 16);
            paggw[(size_t)kk * 66 + 65] = f2bf(eacc2[tid]);   // slot 131 = 0
        }
    }
    if (bk == 0 && tid == 0) offs2[8 * CC] = EE;
    __syncthreads();
    for (int i = tid; i < n; i += 256) {
        uint4 p = st[i];
        uint_t d = p.x >> 17;
        uint_t r = base2[d] + atomicAdd(&cur[d], 1u);
        pkW[s + r] = p.x;
    }
}

// K2c': counting-sort each C-bucket by 5-bit sub key ((u>>2)&31), in place, so the
// dedupe kernels read ONLY their own ~256-entry segment.
__global__ void bucket_sort_C(const uint_t* __restrict__ bbC, uint_t* __restrict__ pkC,
                              uint_t* __restrict__ csub) {
    __shared__ uint_t st[8960];                     // 35.8 KB (bucket mean 8192, +8.5 sigma)
    __shared__ uint_t hist[32], base2[32], cur[32];
    __shared__ uint_t part[256];
    int tid = threadIdx.x, bk = blockIdx.x;
    uint_t s = bbC[bk], epos = bbC[bk + 1];
    int n = (int)(epos - s);
    if (n > 8960) n = 8960;
    if (tid < 32) { hist[tid] = 0; cur[tid] = 0; }
    for (int i = tid; i < n; i += 256) st[i] = pkC[s + i];
    __syncthreads();
    for (int i = tid; i < n; i += 256) atomicAdd(&hist[(st[i] >> 17) & 31u], 1u);
    __syncthreads();
    uint_t h = (tid < 32) ? hist[tid] : 0u;
    part[tid] = h;
    __syncthreads();
    for (int off = 1; off < 256; off <<= 1) {
        uint_t v = (tid >= off) ? part[tid - off] : 0u;
        __syncthreads();
        part[tid] += v;
        __syncthreads();
    }
    if (tid < 32) {
        base2[tid] = part[tid] - h;
        csub[bk * 32 + tid] = s + base2[tid];
    }
    if (bk == 0 && tid == 0) csub[NSEG] = EE;
    __syncthreads();
    for (int i = tid; i < n; i += 256) {
        uint_t w = st[i];
        uint_t d = (w >> 17) & 31u;
        uint_t r = base2[d] + atomicAdd(&cur[d], 1u);
        pkC[s + r] = w;
    }
}

// K3: per cluster: new_pos + new_batch straight to out (enc_emit reads out[O_POS]).
__global__ void cluster_pass(const float* __restrict__ pos, const int* __restrict__ batch,
                             float* __restrict__ out) {
    int c = blockIdx.x * 256 + threadIdx.x;
    if (c >= CC) return;
    float px = 0.f, py = 0.f, pz = 0.f;
    for (int j = 0; j < 4; ++j) {
        int n = c * 4 + j;
        px += pos[n * 3 + 0];
        py += pos[n * 3 + 1];
        pz += pos[n * 3 + 2];
    }
    px *= 0.25f; py *= 0.25f; pz *= 0.25f;
    out[O_POS + c * 3 + 0] = px;
    out[O_POS + c * 3 + 1] = py;
    out[O_POS + c * 3 + 2] = pz;
    int b = batch[c * 4];
    b = max(b, batch[c * 4 + 1]);
    b = max(b, batch[c * 4 + 2]);
    b = max(b, batch[c * 4 + 3]);
    out[O_BATCH + c] = (float)b;
}

// K2d: XCD-affine x-gather reduce. One wave per (slice s, cluster c) segment;
// s = blockIdx&7 pins x-slice s (3.2 MB) to one XCD's L2 (round-5 verified).
// NEW: readfirstlane'd bounds + wave-uniform pkW[i] loads (scalar/broadcast) —
// deletes the per-edge strided-load + ds_bpermute dependency chain of round 8.
__global__ void cluster_reduce4(const uint_t* __restrict__ offs2, const uint_t* __restrict__ pkW,
                                const uint_t* __restrict__ xb, uint_t* __restrict__ paggw) {
    int tid = threadIdx.x;
    int lane = tid & 63;
    int s = blockIdx.x & 7;
    int c = (blockIdx.x >> 3) * 4 + (tid >> 6);     // 0..24999
    uint_t kk = (uint_t)s * CC + (uint_t)c;
    uint_t start = (uint_t)__builtin_amdgcn_readfirstlane((int)offs2[kk]);
    uint_t end   = (uint_t)__builtin_amdgcn_readfirstlane((int)offs2[kk + 1]);
    float a0 = 0.f, a1 = 0.f;
    for (uint_t i = start; i < end; ++i) {
        uint_t wj = pkW[i];                         // wave-uniform -> s_load/broadcast
        uint_t src = wj & 0x1FFFFu;
        uint_t xv = xb[(size_t)src * 64 + lane];    // coalesced 256 B row
        a0 += bf2f((ushort_t)(xv & 0xffffu));
        a1 += bf2f((ushort_t)(xv >> 16));
    }
    paggw[(size_t)kk * 66 + lane] = f2bf(a0) | (f2bf(a1) << 16);
}

// K2e: fold 8 slice-partials -> aggb (f32 sum of bf16 partials, bf16 out).
__global__ void agg_merge(const uint_t* __restrict__ paggw, uint_t* __restrict__ aggw) {
    int j = blockIdx.x * 256 + threadIdx.x;
    if (j >= 1650000) return;
    float lo = 0.f, hi = 0.f;
    #pragma unroll
    for (int s = 0; s < 8; ++s) {
        uint_t w = paggw[(size_t)s * 1650000u + (uint_t)j];
        lo += bf2f((ushort_t)(w & 0xffffu));
        hi += bf2f((ushort_t)(w >> 16));
    }
    aggw[j] = f2bf(lo) | (f2bf(hi) << 16);
}

// K4: x_new[c][o] = 0.25 * sum_{j<131} aggb[c][j] * M1[j][o].
#define GEMM_CPB 32   // clusters per block = 4 iterations of 8
__global__ void gemm_tiled(const ushort_t* __restrict__ aggb, const ushort_t* __restrict__ m1b,
                           float* __restrict__ out) {
    __shared__ ushort_t m1s[131 * 128];            // 33.5 KB bf16
    __shared__ __align__(16) float srowT[132][8];  // 4.2 KB, [j][cluster-in-group]
    int tid = threadIdx.x;
    {
        const uint_t* m1w = (const uint_t*)m1b;
        uint_t* m1sw = (uint_t*)m1s;
        for (int i = tid; i < 131 * 64; i += 256) m1sw[i] = m1w[i];
    }
    int o = tid & 127, half = tid >> 7;
    int c0b = blockIdx.x * GEMM_CPB;
    const uint_t* aggw = (const uint_t*)aggb;      // row = 66 u32 words
    for (int it = 0; it < GEMM_CPB / 8; ++it) {
        int c0 = c0b + it * 8;
        __syncthreads();   // previous-iteration readers done before overwrite
        for (int i = tid; i < 528; i += 256) {
            int cg = i / 66, rem = i - cg * 66;
            int c = c0 + cg;
            uint_t w = (c < CC) ? aggw[(size_t)c * 66 + rem] : 0u;
            srowT[rem * 2][cg]     = bf2f((ushort_t)(w & 0xffffu));
            srowT[rem * 2 + 1][cg] = bf2f((ushort_t)(w >> 16));
        }
        __syncthreads();   // also covers m1s staging on it==0
        float acc0 = 0.f, acc1 = 0.f, acc2 = 0.f, acc3 = 0.f;
        #pragma unroll 4
        for (int j = 0; j < 131; ++j) {
            float m = bf2f(m1s[j * 128 + o]);
            float4 s = *(const float4*)&srowT[j][half * 4];  // broadcast within wave
            acc0 += s.x * m;
            acc1 += s.y * m;
            acc2 += s.z * m;
            acc3 += s.w * m;
        }
        int cb = c0 + half * 4;
        if (cb + 0 < CC) out[O_XNEW + (size_t)(cb + 0) * 128 + o] = 0.25f * acc0;
        if (cb + 1 < CC) out[O_XNEW + (size_t)(cb + 1) * 128 + o] = 0.25f * acc1;
        if (cb + 2 < CC) out[O_XNEW + (size_t)(cb + 2) * 128 + o] = 0.25f * acc2;
        if (cb + 3 < CC) out[O_XNEW + (size_t)(cb + 3) * 128 + o] = 0.25f * acc3;
    }
}

// K6a: per-segment dedupe: read OWN ~256-entry segment, 12.5 KB LDS bitmap
// (4 u-clusters x 25000 v bits), block scan, emit deduped keys (le, rank-dense)
// to kbuf[bid*KCAP] + count. Bitmap built ONCE (emit kernel reads keys, not pkC).
__global__ void enc_count(const uint_t* __restrict__ csub, const uint_t* __restrict__ pkC,
                          uint_t* __restrict__ bcnt, uint_t* __restrict__ kbuf) {
    __shared__ uint_t bmp[3125];
    __shared__ uint_t sh[256];
    int tid = threadIdx.x, bid = blockIdx.x;
    uint_t s = csub[bid], epos = csub[bid + 1];
    int n = (int)(epos - s);
    for (int i = tid; i < 3125; i += 256) bmp[i] = 0;
    __syncthreads();
    for (int i = tid; i < n; i += 256) {
        uint_t w = pkC[s + i];
        uint_t le = ((w >> 15) & 3u) * 25000u + (w & 32767u);
        atomicOr(&bmp[le >> 5], 1u << (le & 31u));
    }
    __syncthreads();
    int lo = tid * 13, hi = lo + 13;
    if (lo > 3125) lo = 3125;
    if (hi > 3125) hi = 3125;
    uint_t mine = 0;
    for (int i = lo; i < hi; ++i) mine += __popc(bmp[i]);
    sh[tid] = mine;
    __syncthreads();
    for (int off = 1; off < 256; off <<= 1) {
        uint_t v = (tid >= off) ? sh[tid - off] : 0u;
        __syncthreads();
        sh[tid] += v;
        __syncthreads();
    }
    uint_t r = sh[tid] - mine;
    uint_t kb = (uint_t)bid * KCAP;
    for (int i = lo; i < hi; ++i) {
        uint_t bits = bmp[i];
        while (bits) {
            int b = __builtin_ctz(bits);
            bits &= bits - 1u;
            if (r < KCAP) kbuf[kb + r] = (uint_t)i * 32u + (uint_t)b;
            r++;
        }
    }
    if (tid == 255) bcnt[bid] = min(sh[255], (uint_t)KCAP);
}

// K6b: decode dense keys, write u/v COALESCED + attrs (np gathers are L2-resident).
// Global order: bid asc (= u-group asc), key asc within (= (u&3, v) asc) ->
// ascending enc, identical to jnp.unique output order.
__global__ void enc_emit(const uint_t* __restrict__ ebase, const uint_t* __restrict__ kbuf,
                         float* __restrict__ out) {
    int tid = threadIdx.x, bid = blockIdx.x;
    uint_t g0 = ebase[bid], g1 = ebase[bid + 1];
    int cnt = (int)(g1 - g0);
    const float* np = out + O_POS;
    uint_t ubase = ((uint_t)(bid >> 5)) * 128u + ((uint_t)(bid & 31)) * 4u;
    uint_t kb = (uint_t)bid * KCAP;
    for (int r = tid; r < cnt; r += 256) {
        uint_t le = kbuf[kb + r];
        uint_t uo = le / 25000u;
        uint_t v = le - uo * 25000u;
        uint_t u = ubase + uo;
        uint_t rank = g0 + (uint_t)r;
        out[O_EI + rank] = (float)u;
        out[O_EI + EE + rank] = (float)v;
        out[O_ATTR + (size_t)rank * 3 + 0] = np[v * 3 + 0] - np[u * 3 + 0];
        out[O_ATTR + (size_t)rank * 3 + 1] = np[v * 3 + 1] - np[u * 3 + 1];
        out[O_ATTR + (size_t)rank * 3 + 2] = np[v * 3 + 2] - np[u * 3 + 2];
    }
}

extern "C" void kernel_launch(void* const* d_in, const int* in_sizes, int n_in,
                              void* d_out, int out_size, void* d_ws, size_t ws_size,
                              hipStream_t stream) {
    const float* x     = (const float*)d_in[0];
    const float* pos   = (const float*)d_in[1];
    const int*   ei    = (const int*)d_in[2];
    const float* ea    = (const float*)d_in[3];
    const int*   batch = (const int*)d_in[4];
    const float* Wconv = (const float*)d_in[5];
    const float* Wedge = (const float*)d_in[6];
    // d_in[7] = D_bloom: dead (bloom_pos never reaches an output)
    const float* Wg    = (const float*)d_in[8];
    // d_in[9] = W_gattr: contribution cancels exactly within each cluster

    float*  out = (float*)d_out;
    uint_t* ws  = (uint_t*)d_ws;

    if (ws_size < (size_t)WS_WORDS * 4) return;

    ushort_t* m1b    = (ushort_t*)(ws + W_M1B);
    ushort_t* aggb   = (ushort_t*)(ws + W_AGGB);
    uint_t*   pkW    = ws + W_AGGB;             // sorted keys alias aggb (dead until agg_merge)
    uint_t*   paggw  = ws + W_PAGG;
    uint4*    pk4    = (uint4*)(ws + W_PKA4);
    uint_t*   pkC    = ws + W_PKC;
    uint_t*   offs2  = ws + W_OFFS2;
    uint_t*   bhA2   = ws + W_BHA2;
    uint_t*   bhC    = ws + W_BHC;
    uint_t*   bbA2   = ws + W_BBA2;
    uint_t*   bcurA2 = ws + W_BCURA2;
    uint_t*   bbC    = ws + W_BBC;
    uint_t*   bcurC  = ws + W_BCURC;
    uint_t*   xb     = (uint_t*)(out + O_EI);   // 6.4M-word bf16-x staging in out region
    // dead-region reuse (valid after bucket_sort_A2 / agg_merge):
    uint_t*   csub   = ws + W_PKA4;             // u32 [NSEG+1]
    uint_t*   bcnt2  = ws + W_PKA4 + 8192u;     // u32 [NSEG]
    uint_t*   ebase2 = ws + W_PKA4 + 16384u;    // u32 [NSEG+1]
    uint_t*   kbuf   = ws + W_PAGG;             // u32 [NSEG*KCAP] = 6.42M <= 13.2M

    hipMemsetAsync(bhA2, 0, (size_t)(NBKT2 + NBKT) * 4, stream);   // bhA2 + bhC contiguous

    xpack<<<dim3(12500), dim3(256), 0, stream>>>((const float4*)x, (uint2*)xb);
    build_m1f<<<dim3(131), dim3(128), 0, stream>>>(Wconv, Wedge, Wg, m1b);
    edge_hist2<<<dim3(256), dim3(256), 0, stream>>>(ei, bhA2, bhC);
    scan_small<<<dim3(1), dim3(256), 0, stream>>>(bhA2, bbA2, bcurA2, NBKT2);
    scan_small<<<dim3(1), dim3(256), 0, stream>>>(bhC, bbC, bcurC, NBKT);
    bucket_place_A2<<<dim3((EE + TPB - 1) / TPB), dim3(256), 0, stream>>>(ei, ea, bcurA2, pk4);
    bucket_place_C<<<dim3((EE + TPB - 1) / TPB), dim3(256), 0, stream>>>(ei, bcurC, pkC);
    bucket_sort_A2<<<dim3(NBKT2), dim3(256), 0, stream>>>(bbA2, pk4, pkW, paggw, offs2);
    cluster_pass<<<dim3(98), dim3(256), 0, stream>>>(pos, batch, out);
    cluster_reduce4<<<dim3(50000), dim3(256), 0, stream>>>(offs2, pkW, xb, paggw);
    agg_merge<<<dim3(6446), dim3(256), 0, stream>>>(paggw, (uint_t*)aggb);
    gemm_tiled<<<dim3((CC + GEMM_CPB - 1) / GEMM_CPB), dim3(256), 0, stream>>>(aggb, m1b, out);
    // x_bf16 staging no longer needed: zero the EI/ATTR region (incl. padding tail)
    hipMemsetAsync((char*)d_out + (size_t)O_EI * 4, 0, (size_t)(3200000 + 4800000) * 4, stream);
    bucket_sort_C<<<dim3(NBKT), dim3(256), 0, stream>>>(bbC, pkC, csub);
    enc_count<<<dim3(NSEG), dim3(256), 0, stream>>>(csub, pkC, bcnt2, kbuf);
    scan_small<<<dim3(1), dim3(256), 0, stream>>>(bcnt2, ebase2, (uint_t*)0, NSEG);
    enc_emit<<<dim3(NSEG), dim3(256), 0, stream>>>(ebase2, kbuf, out);
}

// Round 10
// 472.930 us; speedup vs baseline: 1.0635x; 1.0635x over previous
//
#include <hip/hip_runtime.h>
#include <hip/hip_bf16.h>
#include <stdint.h>

typedef unsigned int uint_t;
typedef unsigned short ushort_t;

#define NN 100000
#define EE 1600000
#define CC 25000
#define DINTER 144
#define NBKT 196          // C-side coarse buckets: src cluster >> 7
#define NBKT2 1568        // A-side buckets: (src_node/12500)*196 + (dst_node>>9)
#define NSEG 6272         // dedupe segments: 196 buckets * 32 subs (4 u-clusters each)
#define KCAP 1024         // keys per segment cap (mean 256, sigma 16 -> +48 sigma)

// ---- ws layout in 32-bit words (total 92.27 MB, proven) ----
#define W_M1B      0u         // u16 [131*128] bf16 m1 = 8384 words
#define W_AGGB     8384u      // bf16[25000*132] = 1,650,000 words (pkW alias pre-agg_merge)
#define W_PAGG     1658384u   // bf16[8][25000*132] = 13,200,000 words (kbuf reuse after agg_merge)
#define W_PKA4     14858384u  // uint4[1,600,000] = 6,400,000 words (csub/bcnt/ebase reuse after sort)
#define W_PKC      21258384u  // u32 [1600000]
#define W_OFFS2    22858384u  // u32 [200001]  per-(slice,cluster) segment offsets
#define W_BHA2     23058385u  // u32 [1568]
#define W_BHC      23059953u  // u32 [196]   (adjacent to BHA2: one memset of 1764)
#define W_BBA2     23060149u  // u32 [1569]
#define W_BCURA2   23061718u  // u32 [1568]
#define W_BBC      23063286u  // u32 [197]
#define W_BCURC    23063483u  // u32 [196]
#define WS_WORDS   23066816u

// ---- out layout in FLOAT32 elements (total 11,300,000) ----
#define O_XNEW  0u
#define O_POS   3200000u
#define O_EI    3275000u
#define O_ATTR  6475000u
#define O_BATCH 11275000u
// x_bf16 staging: first 6.4M words of the O_EI region (re-zeroed before enc_count/emit)
// new_pos f32[25000*3] lives at out[O_POS] and is read back by enc_emit.

static __device__ __forceinline__ uint_t f2bf(float f) {
    union { float f; uint_t i; } v; v.f = f;
    uint_t x = v.i;
    return (x + 0x7fffu + ((x >> 16) & 1u)) >> 16;  // RNE
}
static __device__ __forceinline__ float bf2f(ushort_t u) {
    union { uint_t i; float f; } v; v.i = ((uint_t)u) << 16; return v.f;
}

// K0: pack x (f32) -> bf16x2 words into the output-staging region.
__global__ void xpack(const float4* __restrict__ x4, uint2* __restrict__ xb2) {
    int i = blockIdx.x * 256 + threadIdx.x;
    if (i >= NN * 32) return;            // 12.8M floats / 4
    float4 v = x4[i];
    uint2 r;
    r.x = f2bf(v.x) | (f2bf(v.y) << 16);
    r.y = f2bf(v.z) | (f2bf(v.w) << 16);
    xb2[i] = r;
}

// K1: M1[j][o] = sum_f Wrow_j[f] * Wg[f][o], emitted directly as bf16.
__global__ void build_m1f(const float* __restrict__ Wconv,
                          const float* __restrict__ Wedge,
                          const float* __restrict__ Wg,
                          ushort_t* __restrict__ m1b) {
    int j = blockIdx.x;   // 0..130
    int o = threadIdx.x;  // 0..127
    const float* wrow = (j < 128) ? (Wconv + j * DINTER + 16)
                                  : (Wedge + (j - 128) * DINTER + 16);
    float acc = 0.f;
    for (int f = 0; f < 128; ++f)
        acc += wrow[f] * Wg[f * 128 + o];
    m1b[j * 128 + o] = (ushort_t)f2bf(acc);
}

// K2a: fused coarse histograms (LDS-aggregated).
// hA2: (src_slice, dst_node >> 9).  hC: src cluster >> 7 (dedupe).
__global__ void edge_hist2(const int* __restrict__ ei,
                           uint_t* __restrict__ bhA2, uint_t* __restrict__ bhC) {
    __shared__ uint_t hA[NBKT2], hC[NBKT];
    int tid = threadIdx.x;
    for (int i = tid; i < NBKT2; i += 256) hA[i] = 0;
    for (int i = tid; i < NBKT; i += 256) hC[i] = 0;
    __syncthreads();
    for (int e = blockIdx.x * 256 + tid; e < EE; e += 256 * 256) {
        uint_t u = (uint_t)ei[e];
        uint_t v = (uint_t)ei[EE + e];
        atomicAdd(&hA[(u / 12500u) * 196u + (v >> 9)], 1u);
        atomicAdd(&hC[u >> 9], 1u);
    }
    __syncthreads();
    for (int i = tid; i < NBKT2; i += 256) if (hA[i]) atomicAdd(&bhA2[i], hA[i]);
    for (int i = tid; i < NBKT; i += 256)  if (hC[i]) atomicAdd(&bhC[i], hC[i]);
}

// Single-block exclusive scan. out[0..n] (out[n]=total), optional copy out2[0..n-1].
__global__ void scan_small(const uint_t* __restrict__ in, uint_t* __restrict__ out,
                           uint_t* __restrict__ out2, int n) {
    __shared__ uint_t part[256];
    int tid = threadIdx.x;
    int per = (n + 255) >> 8;
    int lo = tid * per;
    int hi = lo + per; if (hi > n) hi = n;
    if (lo > n) lo = n;
    uint_t s = 0;
    for (int i = lo; i < hi; ++i) s += in[i];
    part[tid] = s;
    __syncthreads();
    for (int off = 1; off < 256; off <<= 1) {
        uint_t v = (tid >= off) ? part[tid - off] : 0u;
        __syncthreads();
        part[tid] += v;
        __syncthreads();
    }
    uint_t run = part[tid] - s;
    for (int i = lo; i < hi; ++i) {
        out[i] = run;
        if (out2) out2[i] = run;
        run += in[i];
    }
    if (tid == 255) out[n] = run;
}

#define TPB 4096
// K2b: bucket scatter for the reduce. Payload uint4 = {(cl<<17)|src, ea.x, ea.y, ea.z}
// so downstream never gathers ei[] or ea[] (both read COALESCED here).
__global__ void bucket_place_A2(const int* __restrict__ ei, const float* __restrict__ ea,
                                uint_t* __restrict__ bcur, uint4* __restrict__ pk4) {
    __shared__ uint_t hist[NBKT2], gbase[NBKT2], cur[NBKT2];
    int tid = threadIdx.x;
    int t0 = blockIdx.x * TPB;
    int nt = EE - t0; if (nt > TPB) nt = TPB;
    for (int i = tid; i < NBKT2; i += 256) { hist[i] = 0; cur[i] = 0; }
    __syncthreads();
    for (int i = tid; i < nt; i += 256) {
        int e = t0 + i;
        uint_t u = (uint_t)ei[e];
        uint_t v = (uint_t)ei[EE + e];
        atomicAdd(&hist[(u / 12500u) * 196u + (v >> 9)], 1u);
    }
    __syncthreads();
    for (int b = tid; b < NBKT2; b += 256) {
        uint_t h = hist[b];
        if (h) gbase[b] = atomicAdd(&bcur[b], h);
    }
    __syncthreads();
    for (int i = tid; i < nt; i += 256) {
        int e = t0 + i;
        uint_t u = (uint_t)ei[e];
        uint_t v = (uint_t)ei[EE + e];
        uint_t b = (u / 12500u) * 196u + (v >> 9);
        uint_t r = gbase[b] + atomicAdd(&cur[b], 1u);
        uint4 p;
        p.x = (((v >> 2) & 127u) << 17) | u;
        p.y = __float_as_uint(ea[(size_t)e * 3 + 0]);
        p.z = __float_as_uint(ea[(size_t)e * 3 + 1]);
        p.w = __float_as_uint(ea[(size_t)e * 3 + 2]);
        pk4[r] = p;
    }
}

// K2b': dedupe-side bucket scatter; full key (u<<15)|v fits u32, bucket = pk>>22.
__global__ void bucket_place_C(const int* __restrict__ ei, uint_t* __restrict__ bcur,
                               uint_t* __restrict__ pkC) {
    __shared__ uint_t pk[TPB];
    __shared__ uint_t gpk[TPB];
    __shared__ uint_t hist[NBKT], lbase[NBKT], gbase[NBKT], cur[NBKT];
    __shared__ uint_t part[256];
    int tid = threadIdx.x;
    int t0 = blockIdx.x * TPB;
    int nt = EE - t0; if (nt > TPB) nt = TPB;
    for (int i = tid; i < NBKT; i += 256) { hist[i] = 0; cur[i] = 0; }
    __syncthreads();
    for (int i = tid; i < nt; i += 256) {
        int e = t0 + i;
        uint_t u = ((uint_t)ei[e]) >> 2;
        uint_t v = ((uint_t)ei[EE + e]) >> 2;
        uint_t w = (u << 15) | v;
        pk[i] = w;
        atomicAdd(&hist[w >> 22], 1u);
    }
    __syncthreads();
    uint_t h = (tid < NBKT) ? hist[tid] : 0u;
    if (tid < NBKT) gbase[tid] = atomicAdd(&bcur[tid], h);
    part[tid] = h;
    __syncthreads();
    for (int off = 1; off < 256; off <<= 1) {
        uint_t v = (tid >= off) ? part[tid - off] : 0u;
        __syncthreads();
        part[tid] += v;
        __syncthreads();
    }
    if (tid < NBKT) lbase[tid] = part[tid] - h;
    __syncthreads();
    for (int i = tid; i < nt; i += 256) {
        uint_t b = pk[i] >> 22;
        uint_t r = lbase[b] + atomicAdd(&cur[b], 1u);
        gpk[r] = pk[i];
    }
    __syncthreads();
    for (int r = tid; r < nt; r += 256) {
        uint_t b = gpk[r] >> 22;
        pkC[gbase[b] + ((uint_t)r - lbase[b])] = gpk[r];
    }
}

// K2c: in-LDS counting sort of each (slice, dst-coarse) bucket by cluster-local id;
// sorted KEYS (.x) written to pkW (aliases aggb, dead until agg_merge).
// ea sums per cluster via LDS FLOAT ATOMICS keyed by the cluster id in the key
// (order-independent — the round-8 sorted-range read of unsorted st[] was wrong).
__global__ void bucket_sort_A2(const uint_t* __restrict__ bbA2, const uint4* __restrict__ pk4,
                               uint_t* __restrict__ pkW, uint_t* __restrict__ paggw,
                               uint_t* __restrict__ offs2) {
    __shared__ uint4 st[2048];                      // 32 KB payload staging
    __shared__ uint_t hist[128], base2[128], cur[128];
    __shared__ float eacc0[128], eacc1[128], eacc2[128];
    __shared__ uint_t part[256];
    int tid = threadIdx.x, bk = blockIdx.x;
    uint_t s = bbA2[bk], epos = bbA2[bk + 1];
    int n = (int)(epos - s);
    if (n > 2048) n = 2048;   // statistically unreachable; guards LDS bounds
    if (tid < 128) {
        hist[tid] = 0; cur[tid] = 0;
        eacc0[tid] = 0.f; eacc1[tid] = 0.f; eacc2[tid] = 0.f;
    }
    for (int i = tid; i < n; i += 256) st[i] = pk4[s + i];
    __syncthreads();
    for (int i = tid; i < n; i += 256) {
        uint4 p = st[i];
        uint_t d = p.x >> 17;
        atomicAdd(&hist[d], 1u);
        atomicAdd(&eacc0[d], __uint_as_float(p.y));
        atomicAdd(&eacc1[d], __uint_as_float(p.z));
        atomicAdd(&eacc2[d], __uint_as_float(p.w));
    }
    __syncthreads();
    uint_t h = (tid < 128) ? hist[tid] : 0u;
    part[tid] = h;
    __syncthreads();
    for (int off = 1; off < 256; off <<= 1) {
        uint_t v = (tid >= off) ? part[tid - off] : 0u;
        __syncthreads();
        part[tid] += v;
        __syncthreads();
    }
    int sl = bk / 196, q = bk - sl * 196;
    if (tid < 128) {
        base2[tid] = part[tid] - h;
        int c = q * 128 + tid;
        if (c < CC) {
            uint_t kk = (uint_t)sl * CC + (uint_t)c;
            offs2[kk] = s + base2[tid];
            paggw[(size_t)kk * 66 + 64] = f2bf(eacc0[tid]) | (f2bf(eacc1[tid]) << 16);
            paggw[(size_t)kk * 66 + 65] = f2bf(eacc2[tid]);   // slot 131 = 0
        }
    }
    if (bk == 0 && tid == 0) offs2[8 * CC] = EE;
    __syncthreads();
    for (int i = tid; i < n; i += 256) {
        uint4 p = st[i];
        uint_t d = p.x >> 17;
        uint_t r = base2[d] + atomicAdd(&cur[d], 1u);
        pkW[s + r] = p.x;
    }
}

// K2c': counting-sort each C-bucket by 5-bit sub key ((u>>2)&31), in place, so the
// dedupe kernels read ONLY their own ~256-entry segment.
__global__ void bucket_sort_C(const uint_t* __restrict__ bbC, uint_t* __restrict__ pkC,
                              uint_t* __restrict__ csub) {
    __shared__ uint_t st[8960];                     // 35.8 KB (bucket mean 8192, +8.5 sigma)
    __shared__ uint_t hist[32], base2[32], cur[32];
    __shared__ uint_t part[256];
    int tid = threadIdx.x, bk = blockIdx.x;
    uint_t s = bbC[bk], epos = bbC[bk + 1];
    int n = (int)(epos - s);
    if (n > 8960) n = 8960;
    if (tid < 32) { hist[tid] = 0; cur[tid] = 0; }
    for (int i = tid; i < n; i += 256) st[i] = pkC[s + i];
    __syncthreads();
    for (int i = tid; i < n; i += 256) atomicAdd(&hist[(st[i] >> 17) & 31u], 1u);
    __syncthreads();
    uint_t h = (tid < 32) ? hist[tid] : 0u;
    part[tid] = h;
    __syncthreads();
    for (int off = 1; off < 256; off <<= 1) {
        uint_t v = (tid >= off) ? part[tid - off] : 0u;
        __syncthreads();
        part[tid] += v;
        __syncthreads();
    }
    if (tid < 32) {
        base2[tid] = part[tid] - h;
        csub[bk * 32 + tid] = s + base2[tid];
    }
    if (bk == 0 && tid == 0) csub[NSEG] = EE;
    __syncthreads();
    for (int i = tid; i < n; i += 256) {
        uint_t w = st[i];
        uint_t d = (w >> 17) & 31u;
        uint_t r = base2[d] + atomicAdd(&cur[d], 1u);
        pkC[s + r] = w;
    }
}

// K3: per cluster: new_pos + new_batch straight to out (enc_emit reads out[O_POS]).
__global__ void cluster_pass(const float* __restrict__ pos, const int* __restrict__ batch,
                             float* __restrict__ out) {
    int c = blockIdx.x * 256 + threadIdx.x;
    if (c >= CC) return;
    float px = 0.f, py = 0.f, pz = 0.f;
    for (int j = 0; j < 4; ++j) {
        int n = c * 4 + j;
        px += pos[n * 3 + 0];
        py += pos[n * 3 + 1];
        pz += pos[n * 3 + 2];
    }
    px *= 0.25f; py *= 0.25f; pz *= 0.25f;
    out[O_POS + c * 3 + 0] = px;
    out[O_POS + c * 3 + 1] = py;
    out[O_POS + c * 3 + 2] = pz;
    int b = batch[c * 4];
    b = max(b, batch[c * 4 + 1]);
    b = max(b, batch[c * 4 + 2]);
    b = max(b, batch[c * 4 + 3]);
    out[O_BATCH + c] = (float)b;
}

// K2d: XCD-affine x-gather reduce. One wave per (slice s, cluster c) segment;
// s = blockIdx&7 pins x-slice s (3.2 MB) to one XCD's L2 (round-5 verified).
// NEW (round 10): unroll-4 with batched consecutive key loads — pkW[i..i+3] merge
// into one s_load_dwordx4, putting 4 independent x-row loads in flight (round 9
// was a serial s_load->v_load chain per edge at ~700 cyc/edge). Accumulation
// stays strictly i-ascending -> bit-identical to round 9.
__global__ void cluster_reduce4(const uint_t* __restrict__ offs2, const uint_t* __restrict__ pkW,
                                const uint_t* __restrict__ xb, uint_t* __restrict__ paggw) {
    int tid = threadIdx.x;
    int lane = tid & 63;
    int s = blockIdx.x & 7;
    int c = (blockIdx.x >> 3) * 4 + (tid >> 6);     // 0..24999
    uint_t kk = (uint_t)s * CC + (uint_t)c;
    uint_t start = (uint_t)__builtin_amdgcn_readfirstlane((int)offs2[kk]);
    uint_t end   = (uint_t)__builtin_amdgcn_readfirstlane((int)offs2[kk + 1]);
    const uint_t* xl = xb + lane;
    float a0 = 0.f, a1 = 0.f;
    uint_t i = start;
    for (; i + 4u <= end; i += 4u) {
        uint_t w0 = pkW[i + 0u];                    // uniform, consecutive -> s_load_dwordx4
        uint_t w1 = pkW[i + 1u];
        uint_t w2 = pkW[i + 2u];
        uint_t w3 = pkW[i + 3u];
        uint_t x0 = xl[(size_t)(w0 & 0x1FFFFu) * 64u];   // 4 independent 256 B row loads
        uint_t x1 = xl[(size_t)(w1 & 0x1FFFFu) * 64u];
        uint_t x2 = xl[(size_t)(w2 & 0x1FFFFu) * 64u];
        uint_t x3 = xl[(size_t)(w3 & 0x1FFFFu) * 64u];
        a0 += bf2f((ushort_t)(x0 & 0xffffu)); a1 += bf2f((ushort_t)(x0 >> 16));
        a0 += bf2f((ushort_t)(x1 & 0xffffu)); a1 += bf2f((ushort_t)(x1 >> 16));
        a0 += bf2f((ushort_t)(x2 & 0xffffu)); a1 += bf2f((ushort_t)(x2 >> 16));
        a0 += bf2f((ushort_t)(x3 & 0xffffu)); a1 += bf2f((ushort_t)(x3 >> 16));
    }
    for (; i < end; ++i) {
        uint_t wj = pkW[i];
        uint_t xv = xl[(size_t)(wj & 0x1FFFFu) * 64u];
        a0 += bf2f((ushort_t)(xv & 0xffffu));
        a1 += bf2f((ushort_t)(xv >> 16));
    }
    paggw[(size_t)kk * 66 + lane] = f2bf(a0) | (f2bf(a1) << 16);
}

// K2e: fold 8 slice-partials -> aggb (f32 sum of bf16 partials, bf16 out).
__global__ void agg_merge(const uint_t* __restrict__ paggw, uint_t* __restrict__ aggw) {
    int j = blockIdx.x * 256 + threadIdx.x;
    if (j >= 1650000) return;
    float lo = 0.f, hi = 0.f;
    #pragma unroll
    for (int s = 0; s < 8; ++s) {
        uint_t w = paggw[(size_t)s * 1650000u + (uint_t)j];
        lo += bf2f((ushort_t)(w & 0xffffu));
        hi += bf2f((ushort_t)(w >> 16));
    }
    aggw[j] = f2bf(lo) | (f2bf(hi) << 16);
}

// K4: x_new[c][o] = 0.25 * sum_{j<131} aggb[c][j] * M1[j][o].
#define GEMM_CPB 32   // clusters per block = 4 iterations of 8
__global__ void gemm_tiled(const ushort_t* __restrict__ aggb, const ushort_t* __restrict__ m1b,
                           float* __restrict__ out) {
    __shared__ ushort_t m1s[131 * 128];            // 33.5 KB bf16
    __shared__ __align__(16) float srowT[132][8];  // 4.2 KB, [j][cluster-in-group]
    int tid = threadIdx.x;
    {
        const uint_t* m1w = (const uint_t*)m1b;
        uint_t* m1sw = (uint_t*)m1s;
        for (int i = tid; i < 131 * 64; i += 256) m1sw[i] = m1w[i];
    }
    int o = tid & 127, half = tid >> 7;
    int c0b = blockIdx.x * GEMM_CPB;
    const uint_t* aggw = (const uint_t*)aggb;      // row = 66 u32 words
    for (int it = 0; it < GEMM_CPB / 8; ++it) {
        int c0 = c0b + it * 8;
        __syncthreads();   // previous-iteration readers done before overwrite
        for (int i = tid; i < 528; i += 256) {
            int cg = i / 66, rem = i - cg * 66;
            int c = c0 + cg;
            uint_t w = (c < CC) ? aggw[(size_t)c * 66 + rem] : 0u;
            srowT[rem * 2][cg]     = bf2f((ushort_t)(w & 0xffffu));
            srowT[rem * 2 + 1][cg] = bf2f((ushort_t)(w >> 16));
        }
        __syncthreads();   // also covers m1s staging on it==0
        float acc0 = 0.f, acc1 = 0.f, acc2 = 0.f, acc3 = 0.f;
        #pragma unroll 4
        for (int j = 0; j < 131; ++j) {
            float m = bf2f(m1s[j * 128 + o]);
            float4 s = *(const float4*)&srowT[j][half * 4];  // broadcast within wave
            acc0 += s.x * m;
            acc1 += s.y * m;
            acc2 += s.z * m;
            acc3 += s.w * m;
        }
        int cb = c0 + half * 4;
        if (cb + 0 < CC) out[O_XNEW + (size_t)(cb + 0) * 128 + o] = 0.25f * acc0;
        if (cb + 1 < CC) out[O_XNEW + (size_t)(cb + 1) * 128 + o] = 0.25f * acc1;
        if (cb + 2 < CC) out[O_XNEW + (size_t)(cb + 2) * 128 + o] = 0.25f * acc2;
        if (cb + 3 < CC) out[O_XNEW + (size_t)(cb + 3) * 128 + o] = 0.25f * acc3;
    }
}

// K6a: per-segment dedupe: read OWN ~256-entry segment, 12.5 KB LDS bitmap
// (4 u-clusters x 25000 v bits), block scan, emit deduped keys (le, rank-dense)
// to kbuf[bid*KCAP] + count. Bitmap built ONCE (emit kernel reads keys, not pkC).
__global__ void enc_count(const uint_t* __restrict__ csub, const uint_t* __restrict__ pkC,
                          uint_t* __restrict__ bcnt, uint_t* __restrict__ kbuf) {
    __shared__ uint_t bmp[3125];
    __shared__ uint_t sh[256];
    int tid = threadIdx.x, bid = blockIdx.x;
    uint_t s = csub[bid], epos = csub[bid + 1];
    int n = (int)(epos - s);
    for (int i = tid; i < 3125; i += 256) bmp[i] = 0;
    __syncthreads();
    for (int i = tid; i < n; i += 256) {
        uint_t w = pkC[s + i];
        uint_t le = ((w >> 15) & 3u) * 25000u + (w & 32767u);
        atomicOr(&bmp[le >> 5], 1u << (le & 31u));
    }
    __syncthreads();
    int lo = tid * 13, hi = lo + 13;
    if (lo > 3125) lo = 3125;
    if (hi > 3125) hi = 3125;
    uint_t mine = 0;
    for (int i = lo; i < hi; ++i) mine += __popc(bmp[i]);
    sh[tid] = mine;
    __syncthreads();
    for (int off = 1; off < 256; off <<= 1) {
        uint_t v = (tid >= off) ? sh[tid - off] : 0u;
        __syncthreads();
        sh[tid] += v;
        __syncthreads();
    }
    uint_t r = sh[tid] - mine;
    uint_t kb = (uint_t)bid * KCAP;
    for (int i = lo; i < hi; ++i) {
        uint_t bits = bmp[i];
        while (bits) {
            int b = __builtin_ctz(bits);
            bits &= bits - 1u;
            if (r < KCAP) kbuf[kb + r] = (uint_t)i * 32u + (uint_t)b;
            r++;
        }
    }
    if (tid == 255) bcnt[bid] = min(sh[255], (uint_t)KCAP);
}

// K6b: decode dense keys, write u/v COALESCED + attrs (np gathers are L2-resident).
// Global order: bid asc (= u-group asc), key asc within (= (u&3, v) asc) ->
// ascending enc, identical to jnp.unique output order.
__global__ void enc_emit(const uint_t* __restrict__ ebase, const uint_t* __restrict__ kbuf,
                         float* __restrict__ out) {
    int tid = threadIdx.x, bid = blockIdx.x;
    uint_t g0 = ebase[bid], g1 = ebase[bid + 1];
    int cnt = (int)(g1 - g0);
    const float* np = out + O_POS;
    uint_t ubase = ((uint_t)(bid >> 5)) * 128u + ((uint_t)(bid & 31)) * 4u;
    uint_t kb = (uint_t)bid * KCAP;
    for (int r = tid; r < cnt; r += 256) {
        uint_t le = kbuf[kb + r];
        uint_t uo = le / 25000u;
        uint_t v = le - uo * 25000u;
        uint_t u = ubase + uo;
        uint_t rank = g0 + (uint_t)r;
        out[O_EI + rank] = (float)u;
        out[O_EI + EE + rank] = (float)v;
        out[O_ATTR + (size_t)rank * 3 + 0] = np[v * 3 + 0] - np[u * 3 + 0];
        out[O_ATTR + (size_t)rank * 3 + 1] = np[v * 3 + 1] - np[u * 3 + 1];
        out[O_ATTR + (size_t)rank * 3 + 2] = np[v * 3 + 2] - np[u * 3 + 2];
    }
}

extern "C" void kernel_launch(void* const* d_in, const int* in_sizes, int n_in,
                              void* d_out, int out_size, void* d_ws, size_t ws_size,
                              hipStream_t stream) {
    const float* x     = (const float*)d_in[0];
    const float* pos   = (const float*)d_in[1];
    const int*   ei    = (const int*)d_in[2];
    const float* ea    = (const float*)d_in[3];
    const int*   batch = (const int*)d_in[4];
    const float* Wconv = (const float*)d_in[5];
    const float* Wedge = (const float*)d_in[6];
    // d_in[7] = D_bloom: dead (bloom_pos never reaches an output)
    const float* Wg    = (const float*)d_in[8];
    // d_in[9] = W_gattr: contribution cancels exactly within each cluster

    float*  out = (float*)d_out;
    uint_t* ws  = (uint_t*)d_ws;

    if (ws_size < (size_t)WS_WORDS * 4) return;

    ushort_t* m1b    = (ushort_t*)(ws + W_M1B);
    ushort_t* aggb   = (ushort_t*)(ws + W_AGGB);
    uint_t*   pkW    = ws + W_AGGB;             // sorted keys alias aggb (dead until agg_merge)
    uint_t*   paggw  = ws + W_PAGG;
    uint4*    pk4    = (uint4*)(ws + W_PKA4);
    uint_t*   pkC    = ws + W_PKC;
    uint_t*   offs2  = ws + W_OFFS2;
    uint_t*   bhA2   = ws + W_BHA2;
    uint_t*   bhC    = ws + W_BHC;
    uint_t*   bbA2   = ws + W_BBA2;
    uint_t*   bcurA2 = ws + W_BCURA2;
    uint_t*   bbC    = ws + W_BBC;
    uint_t*   bcurC  = ws + W_BCURC;
    uint_t*   xb     = (uint_t*)(out + O_EI);   // 6.4M-word bf16-x staging in out region
    // dead-region reuse (valid after bucket_sort_A2 / agg_merge):
    uint_t*   csub   = ws + W_PKA4;             // u32 [NSEG+1]
    uint_t*   bcnt2  = ws + W_PKA4 + 8192u;     // u32 [NSEG]
    uint_t*   ebase2 = ws + W_PKA4 + 16384u;    // u32 [NSEG+1]
    uint_t*   kbuf   = ws + W_PAGG;             // u32 [NSEG*KCAP] = 6.42M <= 13.2M

    hipMemsetAsync(bhA2, 0, (size_t)(NBKT2 + NBKT) * 4, stream);   // bhA2 + bhC contiguous

    xpack<<<dim3(12500), dim3(256), 0, stream>>>((const float4*)x, (uint2*)xb);
    build_m1f<<<dim3(131), dim3(128), 0, stream>>>(Wconv, Wedge, Wg, m1b);
    edge_hist2<<<dim3(256), dim3(256), 0, stream>>>(ei, bhA2, bhC);
    scan_small<<<dim3(1), dim3(256), 0, stream>>>(bhA2, bbA2, bcurA2, NBKT2);
    scan_small<<<dim3(1), dim3(256), 0, stream>>>(bhC, bbC, bcurC, NBKT);
    bucket_place_A2<<<dim3((EE + TPB - 1) / TPB), dim3(256), 0, stream>>>(ei, ea, bcurA2, pk4);
    bucket_place_C<<<dim3((EE + TPB - 1) / TPB), dim3(256), 0, stream>>>(ei, bcurC, pkC);
    bucket_sort_A2<<<dim3(NBKT2), dim3(256), 0, stream>>>(bbA2, pk4, pkW, paggw, offs2);
    cluster_pass<<<dim3(98), dim3(256), 0, stream>>>(pos, batch, out);
    cluster_reduce4<<<dim3(50000), dim3(256), 0, stream>>>(offs2, pkW, xb, paggw);
    agg_merge<<<dim3(6446), dim3(256), 0, stream>>>(paggw, (uint_t*)aggb);
    gemm_tiled<<<dim3((CC + GEMM_CPB - 1) / GEMM_CPB), dim3(256), 0, stream>>>(aggb, m1b, out);
    // x_bf16 staging no longer needed: zero the EI/ATTR region (incl. padding tail)
    hipMemsetAsync((char*)d_out + (size_t)O_EI * 4, 0, (size_t)(3200000 + 4800000) * 4, stream);
    bucket_sort_C<<<dim3(NBKT), dim3(256), 0, stream>>>(bbC, pkC, csub);
    enc_count<<<dim3(NSEG), dim3(256), 0, stream>>>(csub, pkC, bcnt2, kbuf);
    scan_small<<<dim3(1), dim3(256), 0, stream>>>(bcnt2, ebase2, (uint_t*)0, NSEG);
    enc_emit<<<dim3(NSEG), dim3(256), 0, stream>>>(ebase2, kbuf, out);
}

// Round 11
// 454.626 us; speedup vs baseline: 1.1063x; 1.0403x over previous
//
#include <hip/hip_runtime.h>
#include <hip/hip_bf16.h>
#include <stdint.h>

typedef unsigned int uint_t;
typedef unsigned short ushort_t;

#define NN 100000
#define EE 1600000
#define CC 25000
#define DINTER 144
#define NBKT 196          // C-side coarse buckets: src cluster >> 7
#define NBKT2 1568        // A-side buckets: (src_node/12500)*196 + (dst_node>>9)
#define NSEG 6272         // dedupe segments: 196 buckets * 32 subs (4 u-clusters each)
#define KCAP 1024         // keys per segment cap (mean 256, sigma 16 -> +48 sigma)

// ---- ws layout in 32-bit words (total 92.27 MB, proven) ----
#define W_M1B      0u         // u16 [131*128] bf16 m1 = 8384 words
#define W_AGGB     8384u      // bf16[25000*132] = 1,650,000 words (pkW alias pre-agg_merge)
#define W_PAGG     1658384u   // bf16[8][25000*132] = 13,200,000 words (kbuf reuse after agg_merge)
#define W_PKA4     14858384u  // uint4[1,600,000] = 6,400,000 words (csub/bcnt/ebase reuse after sort)
#define W_PKC      21258384u  // u32 [1600000]
#define W_OFFS2    22858384u  // u32 [200001]  per-(slice,cluster) segment offsets
#define W_BHA2     23058385u  // u32 [1568]
#define W_BHC      23059953u  // u32 [196]   (adjacent to BHA2: one memset of 1764)
#define W_BBA2     23060149u  // u32 [1569]
#define W_BCURA2   23061718u  // u32 [1568]
#define W_BBC      23063286u  // u32 [197]
#define W_BCURC    23063483u  // u32 [196]
#define WS_WORDS   23066816u

// ---- out layout in FLOAT32 elements (total 11,300,000) ----
#define O_XNEW  0u
#define O_POS   3200000u
#define O_EI    3275000u
#define O_ATTR  6475000u
#define O_BATCH 11275000u
// x_bf16 staging: first 6.4M words of the O_EI region (re-zeroed before enc_count/emit)
// new_pos f32[25000*3] lives at out[O_POS] and is read back by enc_emit.

static __device__ __forceinline__ uint_t f2bf(float f) {
    union { float f; uint_t i; } v; v.f = f;
    uint_t x = v.i;
    return (x + 0x7fffu + ((x >> 16) & 1u)) >> 16;  // RNE
}
static __device__ __forceinline__ float bf2f(ushort_t u) {
    union { uint_t i; float f; } v; v.i = ((uint_t)u) << 16; return v.f;
}

// K0: pack x (f32) -> bf16x2 words into the output-staging region.
__global__ void xpack(const float4* __restrict__ x4, uint2* __restrict__ xb2) {
    int i = blockIdx.x * 256 + threadIdx.x;
    if (i >= NN * 32) return;            // 12.8M floats / 4
    float4 v = x4[i];
    uint2 r;
    r.x = f2bf(v.x) | (f2bf(v.y) << 16);
    r.y = f2bf(v.z) | (f2bf(v.w) << 16);
    xb2[i] = r;
}

// K1: M1[j][o] = sum_f Wrow_j[f] * Wg[f][o], emitted directly as bf16.
__global__ void build_m1f(const float* __restrict__ Wconv,
                          const float* __restrict__ Wedge,
                          const float* __restrict__ Wg,
                          ushort_t* __restrict__ m1b) {
    int j = blockIdx.x;   // 0..130
    int o = threadIdx.x;  // 0..127
    const float* wrow = (j < 128) ? (Wconv + j * DINTER + 16)
                                  : (Wedge + (j - 128) * DINTER + 16);
    float acc = 0.f;
    for (int f = 0; f < 128; ++f)
        acc += wrow[f] * Wg[f * 128 + o];
    m1b[j * 128 + o] = (ushort_t)f2bf(acc);
}

// K2a: fused coarse histograms (LDS-aggregated). 1024-thread blocks (latency hiding).
// hA2: (src_slice, dst_node >> 9).  hC: src cluster >> 7 (dedupe).
__global__ void edge_hist2(const int* __restrict__ ei,
                           uint_t* __restrict__ bhA2, uint_t* __restrict__ bhC) {
    __shared__ uint_t hA[NBKT2], hC[NBKT];
    int tid = threadIdx.x;
    for (int i = tid; i < NBKT2; i += 1024) hA[i] = 0;
    for (int i = tid; i < NBKT; i += 1024) hC[i] = 0;
    __syncthreads();
    for (int e = blockIdx.x * 1024 + tid; e < EE; e += 256 * 1024) {
        uint_t u = (uint_t)ei[e];
        uint_t v = (uint_t)ei[EE + e];
        atomicAdd(&hA[(u / 12500u) * 196u + (v >> 9)], 1u);
        atomicAdd(&hC[u >> 9], 1u);
    }
    __syncthreads();
    for (int i = tid; i < NBKT2; i += 1024) if (hA[i]) atomicAdd(&bhA2[i], hA[i]);
    for (int i = tid; i < NBKT; i += 1024)  if (hC[i]) atomicAdd(&bhC[i], hC[i]);
}

// Single-block exclusive scan. out[0..n] (out[n]=total), optional copy out2[0..n-1].
__global__ void scan_small(const uint_t* __restrict__ in, uint_t* __restrict__ out,
                           uint_t* __restrict__ out2, int n) {
    __shared__ uint_t part[256];
    int tid = threadIdx.x;
    int per = (n + 255) >> 8;
    int lo = tid * per;
    int hi = lo + per; if (hi > n) hi = n;
    if (lo > n) lo = n;
    uint_t s = 0;
    for (int i = lo; i < hi; ++i) s += in[i];
    part[tid] = s;
    __syncthreads();
    for (int off = 1; off < 256; off <<= 1) {
        uint_t v = (tid >= off) ? part[tid - off] : 0u;
        __syncthreads();
        part[tid] += v;
        __syncthreads();
    }
    uint_t run = part[tid] - s;
    for (int i = lo; i < hi; ++i) {
        out[i] = run;
        if (out2) out2[i] = run;
        run += in[i];
    }
    if (tid == 255) out[n] = run;
}

#define TPB 4096
// K2b: bucket scatter for the reduce. Payload uint4 = {(cl<<17)|src, ea.x, ea.y, ea.z}
// so downstream never gathers ei[] or ea[] (both read COALESCED here). 1024-thread
// blocks: round-10 counters showed 256-thread/391-block config at 13.9% occupancy,
// 1.8% VALUBusy — pure latency starvation. Same tiling, 4x the waves in flight.
__global__ void bucket_place_A2(const int* __restrict__ ei, const float* __restrict__ ea,
                                uint_t* __restrict__ bcur, uint4* __restrict__ pk4) {
    __shared__ uint_t hist[NBKT2], gbase[NBKT2], cur[NBKT2];
    int tid = threadIdx.x;
    int t0 = blockIdx.x * TPB;
    int nt = EE - t0; if (nt > TPB) nt = TPB;
    for (int i = tid; i < NBKT2; i += 1024) { hist[i] = 0; cur[i] = 0; }
    __syncthreads();
    for (int i = tid; i < nt; i += 1024) {
        int e = t0 + i;
        uint_t u = (uint_t)ei[e];
        uint_t v = (uint_t)ei[EE + e];
        atomicAdd(&hist[(u / 12500u) * 196u + (v >> 9)], 1u);
    }
    __syncthreads();
    for (int b = tid; b < NBKT2; b += 1024) {
        uint_t h = hist[b];
        if (h) gbase[b] = atomicAdd(&bcur[b], h);
    }
    __syncthreads();
    for (int i = tid; i < nt; i += 1024) {
        int e = t0 + i;
        uint_t u = (uint_t)ei[e];
        uint_t v = (uint_t)ei[EE + e];
        uint_t b = (u / 12500u) * 196u + (v >> 9);
        uint_t r = gbase[b] + atomicAdd(&cur[b], 1u);
        uint4 p;
        p.x = (((v >> 2) & 127u) << 17) | u;
        p.y = __float_as_uint(ea[(size_t)e * 3 + 0]);
        p.z = __float_as_uint(ea[(size_t)e * 3 + 1]);
        p.w = __float_as_uint(ea[(size_t)e * 3 + 2]);
        pk4[r] = p;
    }
}

// K2b': dedupe-side bucket scatter; full key (u<<15)|v fits u32, bucket = pk>>22.
// 1024-thread blocks; scan widened to 1024 lanes.
__global__ void bucket_place_C(const int* __restrict__ ei, uint_t* __restrict__ bcur,
                               uint_t* __restrict__ pkC) {
    __shared__ uint_t pk[TPB];
    __shared__ uint_t gpk[TPB];
    __shared__ uint_t hist[NBKT], lbase[NBKT], gbase[NBKT], cur[NBKT];
    __shared__ uint_t part[1024];
    int tid = threadIdx.x;
    int t0 = blockIdx.x * TPB;
    int nt = EE - t0; if (nt > TPB) nt = TPB;
    for (int i = tid; i < NBKT; i += 1024) { hist[i] = 0; cur[i] = 0; }
    __syncthreads();
    for (int i = tid; i < nt; i += 1024) {
        int e = t0 + i;
        uint_t u = ((uint_t)ei[e]) >> 2;
        uint_t v = ((uint_t)ei[EE + e]) >> 2;
        uint_t w = (u << 15) | v;
        pk[i] = w;
        atomicAdd(&hist[w >> 22], 1u);
    }
    __syncthreads();
    uint_t h = (tid < NBKT) ? hist[tid] : 0u;
    if (tid < NBKT) gbase[tid] = atomicAdd(&bcur[tid], h);
    part[tid] = h;
    __syncthreads();
    for (int off = 1; off < 1024; off <<= 1) {
        uint_t v = (tid >= off) ? part[tid - off] : 0u;
        __syncthreads();
        part[tid] += v;
        __syncthreads();
    }
    if (tid < NBKT) lbase[tid] = part[tid] - h;
    __syncthreads();
    for (int i = tid; i < nt; i += 1024) {
        uint_t b = pk[i] >> 22;
        uint_t r = lbase[b] + atomicAdd(&cur[b], 1u);
        gpk[r] = pk[i];
    }
    __syncthreads();
    for (int r = tid; r < nt; r += 1024) {
        uint_t b = gpk[r] >> 22;
        pkC[gbase[b] + ((uint_t)r - lbase[b])] = gpk[r];
    }
}

// K2c: in-LDS counting sort of each (slice, dst-coarse) bucket by cluster-local id;
// sorted KEYS (.x) written to pkW (aliases aggb, dead until agg_merge).
// ea sums per cluster via LDS FLOAT ATOMICS keyed by the cluster id in the key
// (order-independent — the round-8 sorted-range read of unsorted st[] was wrong).
__global__ void bucket_sort_A2(const uint_t* __restrict__ bbA2, const uint4* __restrict__ pk4,
                               uint_t* __restrict__ pkW, uint_t* __restrict__ paggw,
                               uint_t* __restrict__ offs2) {
    __shared__ uint4 st[2048];                      // 32 KB payload staging
    __shared__ uint_t hist[128], base2[128], cur[128];
    __shared__ float eacc0[128], eacc1[128], eacc2[128];
    __shared__ uint_t part[256];
    int tid = threadIdx.x, bk = blockIdx.x;
    uint_t s = bbA2[bk], epos = bbA2[bk + 1];
    int n = (int)(epos - s);
    if (n > 2048) n = 2048;   // statistically unreachable; guards LDS bounds
    if (tid < 128) {
        hist[tid] = 0; cur[tid] = 0;
        eacc0[tid] = 0.f; eacc1[tid] = 0.f; eacc2[tid] = 0.f;
    }
    for (int i = tid; i < n; i += 256) st[i] = pk4[s + i];
    __syncthreads();
    for (int i = tid; i < n; i += 256) {
        uint4 p = st[i];
        uint_t d = p.x >> 17;
        atomicAdd(&hist[d], 1u);
        atomicAdd(&eacc0[d], __uint_as_float(p.y));
        atomicAdd(&eacc1[d], __uint_as_float(p.z));
        atomicAdd(&eacc2[d], __uint_as_float(p.w));
    }
    __syncthreads();
    uint_t h = (tid < 128) ? hist[tid] : 0u;
    part[tid] = h;
    __syncthreads();
    for (int off = 1; off < 256; off <<= 1) {
        uint_t v = (tid >= off) ? part[tid - off] : 0u;
        __syncthreads();
        part[tid] += v;
        __syncthreads();
    }
    int sl = bk / 196, q = bk - sl * 196;
    if (tid < 128) {
        base2[tid] = part[tid] - h;
        int c = q * 128 + tid;
        if (c < CC) {
            uint_t kk = (uint_t)sl * CC + (uint_t)c;
            offs2[kk] = s + base2[tid];
            paggw[(size_t)kk * 66 + 64] = f2bf(eacc0[tid]) | (f2bf(eacc1[tid]) << 16);
            paggw[(size_t)kk * 66 + 65] = f2bf(eacc2[tid]);   // slot 131 = 0
        }
    }
    if (bk == 0 && tid == 0) offs2[8 * CC] = EE;
    __syncthreads();
    for (int i = tid; i < n; i += 256) {
        uint4 p = st[i];
        uint_t d = p.x >> 17;
        uint_t r = base2[d] + atomicAdd(&cur[d], 1u);
        pkW[s + r] = p.x;
    }
}

// K2c': counting-sort each C-bucket by 5-bit sub key ((u>>2)&31), in place, so the
// dedupe kernels read ONLY their own ~256-entry segment.
__global__ void bucket_sort_C(const uint_t* __restrict__ bbC, uint_t* __restrict__ pkC,
                              uint_t* __restrict__ csub) {
    __shared__ uint_t st[8960];                     // 35.8 KB (bucket mean 8192, +8.5 sigma)
    __shared__ uint_t hist[32], base2[32], cur[32];
    __shared__ uint_t part[256];
    int tid = threadIdx.x, bk = blockIdx.x;
    uint_t s = bbC[bk], epos = bbC[bk + 1];
    int n = (int)(epos - s);
    if (n > 8960) n = 8960;
    if (tid < 32) { hist[tid] = 0; cur[tid] = 0; }
    for (int i = tid; i < n; i += 256) st[i] = pkC[s + i];
    __syncthreads();
    for (int i = tid; i < n; i += 256) atomicAdd(&hist[(st[i] >> 17) & 31u], 1u);
    __syncthreads();
    uint_t h = (tid < 32) ? hist[tid] : 0u;
    part[tid] = h;
    __syncthreads();
    for (int off = 1; off < 256; off <<= 1) {
        uint_t v = (tid >= off) ? part[tid - off] : 0u;
        __syncthreads();
        part[tid] += v;
        __syncthreads();
    }
    if (tid < 32) {
        base2[tid] = part[tid] - h;
        csub[bk * 32 + tid] = s + base2[tid];
    }
    if (bk == 0 && tid == 0) csub[NSEG] = EE;
    __syncthreads();
    for (int i = tid; i < n; i += 256) {
        uint_t w = st[i];
        uint_t d = (w >> 17) & 31u;
        uint_t r = base2[d] + atomicAdd(&cur[d], 1u);
        pkC[s + r] = w;
    }
}

// K3: per cluster: new_pos + new_batch straight to out (enc_emit reads out[O_POS]).
__global__ void cluster_pass(const float* __restrict__ pos, const int* __restrict__ batch,
                             float* __restrict__ out) {
    int c = blockIdx.x * 256 + threadIdx.x;
    if (c >= CC) return;
    float px = 0.f, py = 0.f, pz = 0.f;
    for (int j = 0; j < 4; ++j) {
        int n = c * 4 + j;
        px += pos[n * 3 + 0];
        py += pos[n * 3 + 1];
        pz += pos[n * 3 + 2];
    }
    px *= 0.25f; py *= 0.25f; pz *= 0.25f;
    out[O_POS + c * 3 + 0] = px;
    out[O_POS + c * 3 + 1] = py;
    out[O_POS + c * 3 + 2] = pz;
    int b = batch[c * 4];
    b = max(b, batch[c * 4 + 1]);
    b = max(b, batch[c * 4 + 2]);
    b = max(b, batch[c * 4 + 3]);
    out[O_BATCH + c] = (float)b;
}

// K2d: XCD-affine x-gather reduce. One wave per (slice s, cluster c) segment;
// s = blockIdx&7 pins x-slice s (3.2 MB) to one XCD's L2 (round-5 verified).
// Unroll-4 with batched consecutive key loads (s_load_dwordx4, 4 row loads in
// flight) — round-10 verified: 86 -> ~66 us. Accumulation strictly i-ascending.
__global__ void cluster_reduce4(const uint_t* __restrict__ offs2, const uint_t* __restrict__ pkW,
                                const uint_t* __restrict__ xb, uint_t* __restrict__ paggw) {
    int tid = threadIdx.x;
    int lane = tid & 63;
    int s = blockIdx.x & 7;
    int c = (blockIdx.x >> 3) * 4 + (tid >> 6);     // 0..24999
    uint_t kk = (uint_t)s * CC + (uint_t)c;
    uint_t start = (uint_t)__builtin_amdgcn_readfirstlane((int)offs2[kk]);
    uint_t end   = (uint_t)__builtin_amdgcn_readfirstlane((int)offs2[kk + 1]);
    const uint_t* xl = xb + lane;
    float a0 = 0.f, a1 = 0.f;
    uint_t i = start;
    for (; i + 4u <= end; i += 4u) {
        uint_t w0 = pkW[i + 0u];                    // uniform, consecutive -> s_load_dwordx4
        uint_t w1 = pkW[i + 1u];
        uint_t w2 = pkW[i + 2u];
        uint_t w3 = pkW[i + 3u];
        uint_t x0 = xl[(size_t)(w0 & 0x1FFFFu) * 64u];   // 4 independent 256 B row loads
        uint_t x1 = xl[(size_t)(w1 & 0x1FFFFu) * 64u];
        uint_t x2 = xl[(size_t)(w2 & 0x1FFFFu) * 64u];
        uint_t x3 = xl[(size_t)(w3 & 0x1FFFFu) * 64u];
        a0 += bf2f((ushort_t)(x0 & 0xffffu)); a1 += bf2f((ushort_t)(x0 >> 16));
        a0 += bf2f((ushort_t)(x1 & 0xffffu)); a1 += bf2f((ushort_t)(x1 >> 16));
        a0 += bf2f((ushort_t)(x2 & 0xffffu)); a1 += bf2f((ushort_t)(x2 >> 16));
        a0 += bf2f((ushort_t)(x3 & 0xffffu)); a1 += bf2f((ushort_t)(x3 >> 16));
    }
    for (; i < end; ++i) {
        uint_t wj = pkW[i];
        uint_t xv = xl[(size_t)(wj & 0x1FFFFu) * 64u];
        a0 += bf2f((ushort_t)(xv & 0xffffu));
        a1 += bf2f((ushort_t)(xv >> 16));
    }
    paggw[(size_t)kk * 66 + lane] = f2bf(a0) | (f2bf(a1) << 16);
}

// K2e: fold 8 slice-partials -> aggb (f32 sum of bf16 partials, bf16 out).
__global__ void agg_merge(const uint_t* __restrict__ paggw, uint_t* __restrict__ aggw) {
    int j = blockIdx.x * 256 + threadIdx.x;
    if (j >= 1650000) return;
    float lo = 0.f, hi = 0.f;
    #pragma unroll
    for (int s = 0; s < 8; ++s) {
        uint_t w = paggw[(size_t)s * 1650000u + (uint_t)j];
        lo += bf2f((ushort_t)(w & 0xffffu));
        hi += bf2f((ushort_t)(w >> 16));
    }
    aggw[j] = f2bf(lo) | (f2bf(hi) << 16);
}

// K4: x_new[c][o] = 0.25 * sum_{j<131} aggb[c][j] * M1[j][o].
#define GEMM_CPB 32   // clusters per block = 4 iterations of 8
__global__ void gemm_tiled(const ushort_t* __restrict__ aggb, const ushort_t* __restrict__ m1b,
                           float* __restrict__ out) {
    __shared__ ushort_t m1s[131 * 128];            // 33.5 KB bf16
    __shared__ __align__(16) float srowT[132][8];  // 4.2 KB, [j][cluster-in-group]
    int tid = threadIdx.x;
    {
        const uint_t* m1w = (const uint_t*)m1b;
        uint_t* m1sw = (uint_t*)m1s;
        for (int i = tid; i < 131 * 64; i += 256) m1sw[i] = m1w[i];
    }
    int o = tid & 127, half = tid >> 7;
    int c0b = blockIdx.x * GEMM_CPB;
    const uint_t* aggw = (const uint_t*)aggb;      // row = 66 u32 words
    for (int it = 0; it < GEMM_CPB / 8; ++it) {
        int c0 = c0b + it * 8;
        __syncthreads();   // previous-iteration readers done before overwrite
        for (int i = tid; i < 528; i += 256) {
            int cg = i / 66, rem = i - cg * 66;
            int c = c0 + cg;
            uint_t w = (c < CC) ? aggw[(size_t)c * 66 + rem] : 0u;
            srowT[rem * 2][cg]     = bf2f((ushort_t)(w & 0xffffu));
            srowT[rem * 2 + 1][cg] = bf2f((ushort_t)(w >> 16));
        }
        __syncthreads();   // also covers m1s staging on it==0
        float acc0 = 0.f, acc1 = 0.f, acc2 = 0.f, acc3 = 0.f;
        #pragma unroll 4
        for (int j = 0; j < 131; ++j) {
            float m = bf2f(m1s[j * 128 + o]);
            float4 s = *(const float4*)&srowT[j][half * 4];  // broadcast within wave
            acc0 += s.x * m;
            acc1 += s.y * m;
            acc2 += s.z * m;
            acc3 += s.w * m;
        }
        int cb = c0 + half * 4;
        if (cb + 0 < CC) out[O_XNEW + (size_t)(cb + 0) * 128 + o] = 0.25f * acc0;
        if (cb + 1 < CC) out[O_XNEW + (size_t)(cb + 1) * 128 + o] = 0.25f * acc1;
        if (cb + 2 < CC) out[O_XNEW + (size_t)(cb + 2) * 128 + o] = 0.25f * acc2;
        if (cb + 3 < CC) out[O_XNEW + (size_t)(cb + 3) * 128 + o] = 0.25f * acc3;
    }
}

// K6a: per-segment dedupe: read OWN ~256-entry segment, 12.5 KB LDS bitmap
// (4 u-clusters x 25000 v bits), block scan, emit deduped keys (le, rank-dense)
// to kbuf[bid*KCAP] + count. Bitmap built ONCE (emit kernel reads keys, not pkC).
__global__ void enc_count(const uint_t* __restrict__ csub, const uint_t* __restrict__ pkC,
                          uint_t* __restrict__ bcnt, uint_t* __restrict__ kbuf) {
    __shared__ uint_t bmp[3125];
    __shared__ uint_t sh[256];
    int tid = threadIdx.x, bid = blockIdx.x;
    uint_t s = csub[bid], epos = csub[bid + 1];
    int n = (int)(epos - s);
    for (int i = tid; i < 3125; i += 256) bmp[i] = 0;
    __syncthreads();
    for (int i = tid; i < n; i += 256) {
        uint_t w = pkC[s + i];
        uint_t le = ((w >> 15) & 3u) * 25000u + (w & 32767u);
        atomicOr(&bmp[le >> 5], 1u << (le & 31u));
    }
    __syncthreads();
    int lo = tid * 13, hi = lo + 13;
    if (lo > 3125) lo = 3125;
    if (hi > 3125) hi = 3125;
    uint_t mine = 0;
    for (int i = lo; i < hi; ++i) mine += __popc(bmp[i]);
    sh[tid] = mine;
    __syncthreads();
    for (int off = 1; off < 256; off <<= 1) {
        uint_t v = (tid >= off) ? sh[tid - off] : 0u;
        __syncthreads();
        sh[tid] += v;
        __syncthreads();
    }
    uint_t r = sh[tid] - mine;
    uint_t kb = (uint_t)bid * KCAP;
    for (int i = lo; i < hi; ++i) {
        uint_t bits = bmp[i];
        while (bits) {
            int b = __builtin_ctz(bits);
            bits &= bits - 1u;
            if (r < KCAP) kbuf[kb + r] = (uint_t)i * 32u + (uint_t)b;
            r++;
        }
    }
    if (tid == 255) bcnt[bid] = min(sh[255], (uint_t)KCAP);
}

// K6b: decode dense keys, write u/v COALESCED + attrs (np gathers are L2-resident).
// Global order: bid asc (= u-group asc), key asc within (= (u&3, v) asc) ->
// ascending enc, identical to jnp.unique output order.
__global__ void enc_emit(const uint_t* __restrict__ ebase, const uint_t* __restrict__ kbuf,
                         float* __restrict__ out) {
    int tid = threadIdx.x, bid = blockIdx.x;
    uint_t g0 = ebase[bid], g1 = ebase[bid + 1];
    int cnt = (int)(g1 - g0);
    const float* np = out + O_POS;
    uint_t ubase = ((uint_t)(bid >> 5)) * 128u + ((uint_t)(bid & 31)) * 4u;
    uint_t kb = (uint_t)bid * KCAP;
    for (int r = tid; r < cnt; r += 256) {
        uint_t le = kbuf[kb + r];
        uint_t uo = le / 25000u;
        uint_t v = le - uo * 25000u;
        uint_t u = ubase + uo;
        uint_t rank = g0 + (uint_t)r;
        out[O_EI + rank] = (float)u;
        out[O_EI + EE + rank] = (float)v;
        out[O_ATTR + (size_t)rank * 3 + 0] = np[v * 3 + 0] - np[u * 3 + 0];
        out[O_ATTR + (size_t)rank * 3 + 1] = np[v * 3 + 1] - np[u * 3 + 1];
        out[O_ATTR + (size_t)rank * 3 + 2] = np[v * 3 + 2] - np[u * 3 + 2];
    }
}

extern "C" void kernel_launch(void* const* d_in, const int* in_sizes, int n_in,
                              void* d_out, int out_size, void* d_ws, size_t ws_size,
                              hipStream_t stream) {
    const float* x     = (const float*)d_in[0];
    const float* pos   = (const float*)d_in[1];
    const int*   ei    = (const int*)d_in[2];
    const float* ea    = (const float*)d_in[3];
    const int*   batch = (const int*)d_in[4];
    const float* Wconv = (const float*)d_in[5];
    const float* Wedge = (const float*)d_in[6];
    // d_in[7] = D_bloom: dead (bloom_pos never reaches an output)
    const float* Wg    = (const float*)d_in[8];
    // d_in[9] = W_gattr: contribution cancels exactly within each cluster

    float*  out = (float*)d_out;
    uint_t* ws  = (uint_t*)d_ws;

    if (ws_size < (size_t)WS_WORDS * 4) return;

    ushort_t* m1b    = (ushort_t*)(ws + W_M1B);
    ushort_t* aggb   = (ushort_t*)(ws + W_AGGB);
    uint_t*   pkW    = ws + W_AGGB;             // sorted keys alias aggb (dead until agg_merge)
    uint_t*   paggw  = ws + W_PAGG;
    uint4*    pk4    = (uint4*)(ws + W_PKA4);
    uint_t*   pkC    = ws + W_PKC;
    uint_t*   offs2  = ws + W_OFFS2;
    uint_t*   bhA2   = ws + W_BHA2;
    uint_t*   bhC    = ws + W_BHC;
    uint_t*   bbA2   = ws + W_BBA2;
    uint_t*   bcurA2 = ws + W_BCURA2;
    uint_t*   bbC    = ws + W_BBC;
    uint_t*   bcurC  = ws + W_BCURC;
    uint_t*   xb     = (uint_t*)(out + O_EI);   // 6.4M-word bf16-x staging in out region
    // dead-region reuse (valid after bucket_sort_A2 / agg_merge):
    uint_t*   csub   = ws + W_PKA4;             // u32 [NSEG+1]
    uint_t*   bcnt2  = ws + W_PKA4 + 8192u;     // u32 [NSEG]
    uint_t*   ebase2 = ws + W_PKA4 + 16384u;    // u32 [NSEG+1]
    uint_t*   kbuf   = ws + W_PAGG;             // u32 [NSEG*KCAP] = 6.42M <= 13.2M

    hipMemsetAsync(bhA2, 0, (size_t)(NBKT2 + NBKT) * 4, stream);   // bhA2 + bhC contiguous

    xpack<<<dim3(12500), dim3(256), 0, stream>>>((const float4*)x, (uint2*)xb);
    build_m1f<<<dim3(131), dim3(128), 0, stream>>>(Wconv, Wedge, Wg, m1b);
    edge_hist2<<<dim3(256), dim3(1024), 0, stream>>>(ei, bhA2, bhC);
    scan_small<<<dim3(1), dim3(256), 0, stream>>>(bhA2, bbA2, bcurA2, NBKT2);
    scan_small<<<dim3(1), dim3(256), 0, stream>>>(bhC, bbC, bcurC, NBKT);
    bucket_place_A2<<<dim3((EE + TPB - 1) / TPB), dim3(1024), 0, stream>>>(ei, ea, bcurA2, pk4);
    bucket_place_C<<<dim3((EE + TPB - 1) / TPB), dim3(1024), 0, stream>>>(ei, bcurC, pkC);
    bucket_sort_A2<<<dim3(NBKT2), dim3(256), 0, stream>>>(bbA2, pk4, pkW, paggw, offs2);
    cluster_pass<<<dim3(98), dim3(256), 0, stream>>>(pos, batch, out);
    cluster_reduce4<<<dim3(50000), dim3(256), 0, stream>>>(offs2, pkW, xb, paggw);
    agg_merge<<<dim3(6446), dim3(256), 0, stream>>>(paggw, (uint_t*)aggb);
    gemm_tiled<<<dim3((CC + GEMM_CPB - 1) / GEMM_CPB), dim3(256), 0, stream>>>(aggb, m1b, out);
    // x_bf16 staging no longer needed: zero the EI/ATTR region (incl. padding tail)
    hipMemsetAsync((char*)d_out + (size_t)O_EI * 4, 0, (size_t)(3200000 + 4800000) * 4, stream);
    bucket_sort_C<<<dim3(NBKT), dim3(256), 0, stream>>>(bbC, pkC, csub);
    enc_count<<<dim3(NSEG), dim3(256), 0, stream>>>(csub, pkC, bcnt2, kbuf);
    scan_small<<<dim3(1), dim3(256), 0, stream>>>(bcnt2, ebase2, (uint_t*)0, NSEG);
    enc_emit<<<dim3(NSEG), dim3(256), 0, stream>>>(ebase2, kbuf, out);
}

// Round 12
// 431.591 us; speedup vs baseline: 1.1654x; 1.0534x over previous
//
#include <hip/hip_runtime.h>
#include <hip/hip_bf16.h>
#include <stdint.h>

typedef unsigned int uint_t;
typedef unsigned short ushort_t;

#define NN 100000
#define EE 1600000
#define CC 25000
#define DINTER 144
#define NBKT 196          // C-side coarse buckets: src cluster >> 7
#define NBKT2 1568        // A-side buckets: (src_node/12500)*196 + (dst_node>>9)
#define NSEG 6272         // dedupe segments: 196 buckets * 32 subs (4 u-clusters each)
#define KCAP 1024         // keys per segment cap (mean 256, sigma 16 -> +48 sigma)

// ---- ws layout in 32-bit words (total 92.27 MB, proven) ----
#define W_M1B      0u         // u16 [131*128] bf16 m1 = 8384 words
#define W_AGGB     8384u      // pkW sorted keys region (u32 [1,600,000] fits in 1,650,000)
#define W_PAGG     1658384u   // bf16[8][25000*132] = 13,200,000 words (kbuf reuse after gemm)
#define W_PKA4     14858384u  // uint4[1,600,000] = 6,400,000 words (csub/bcnt/ebase reuse after sort)
#define W_PKC      21258384u  // u32 [1600000]
#define W_OFFS2    22858384u  // u32 [200001]  per-(slice,cluster) segment offsets
#define W_BHA2     23058385u  // u32 [1568]
#define W_BHC      23059953u  // u32 [196]   (adjacent to BHA2: one memset of 1764)
#define W_BBA2     23060149u  // u32 [1569]
#define W_BCURA2   23061718u  // u32 [1568]
#define W_BBC      23063286u  // u32 [197]
#define W_BCURC    23063483u  // u32 [196]
#define WS_WORDS   23066816u

// ---- out layout in FLOAT32 elements (total 11,300,000) ----
#define O_XNEW  0u
#define O_POS   3200000u
#define O_EI    3275000u
#define O_ATTR  6475000u
#define O_BATCH 11275000u
// x_bf16 staging: first 6.4M words of the O_EI region (re-zeroed before enc_count/emit)
// new_pos f32[25000*3] lives at out[O_POS] and is read back by enc_emit.

static __device__ __forceinline__ uint_t f2bf(float f) {
    union { float f; uint_t i; } v; v.f = f;
    uint_t x = v.i;
    return (x + 0x7fffu + ((x >> 16) & 1u)) >> 16;  // RNE
}
static __device__ __forceinline__ float bf2f(ushort_t u) {
    union { uint_t i; float f; } v; v.i = ((uint_t)u) << 16; return v.f;
}

// K0: pack x (f32) -> bf16x2 words into the output-staging region.
__global__ void xpack(const float4* __restrict__ x4, uint2* __restrict__ xb2) {
    int i = blockIdx.x * 256 + threadIdx.x;
    if (i >= NN * 32) return;            // 12.8M floats / 4
    float4 v = x4[i];
    uint2 r;
    r.x = f2bf(v.x) | (f2bf(v.y) << 16);
    r.y = f2bf(v.z) | (f2bf(v.w) << 16);
    xb2[i] = r;
}

// K1: M1[j][o] = sum_f Wrow_j[f] * Wg[f][o], emitted directly as bf16.
__global__ void build_m1f(const float* __restrict__ Wconv,
                          const float* __restrict__ Wedge,
                          const float* __restrict__ Wg,
                          ushort_t* __restrict__ m1b) {
    int j = blockIdx.x;   // 0..130
    int o = threadIdx.x;  // 0..127
    const float* wrow = (j < 128) ? (Wconv + j * DINTER + 16)
                                  : (Wedge + (j - 128) * DINTER + 16);
    float acc = 0.f;
    for (int f = 0; f < 128; ++f)
        acc += wrow[f] * Wg[f * 128 + o];
    m1b[j * 128 + o] = (ushort_t)f2bf(acc);
}

// K2a: fused coarse histograms (LDS-aggregated). 1024-thread blocks.
__global__ void edge_hist2(const int* __restrict__ ei,
                           uint_t* __restrict__ bhA2, uint_t* __restrict__ bhC) {
    __shared__ uint_t hA[NBKT2], hC[NBKT];
    int tid = threadIdx.x;
    for (int i = tid; i < NBKT2; i += 1024) hA[i] = 0;
    for (int i = tid; i < NBKT; i += 1024) hC[i] = 0;
    __syncthreads();
    for (int e = blockIdx.x * 1024 + tid; e < EE; e += 256 * 1024) {
        uint_t u = (uint_t)ei[e];
        uint_t v = (uint_t)ei[EE + e];
        atomicAdd(&hA[(u / 12500u) * 196u + (v >> 9)], 1u);
        atomicAdd(&hC[u >> 9], 1u);
    }
    __syncthreads();
    for (int i = tid; i < NBKT2; i += 1024) if (hA[i]) atomicAdd(&bhA2[i], hA[i]);
    for (int i = tid; i < NBKT; i += 1024)  if (hC[i]) atomicAdd(&bhC[i], hC[i]);
}

// Single-block exclusive scan. out[0..n] (out[n]=total), optional copy out2[0..n-1].
__global__ void scan_small(const uint_t* __restrict__ in, uint_t* __restrict__ out,
                           uint_t* __restrict__ out2, int n) {
    __shared__ uint_t part[256];
    int tid = threadIdx.x;
    int per = (n + 255) >> 8;
    int lo = tid * per;
    int hi = lo + per; if (hi > n) hi = n;
    if (lo > n) lo = n;
    uint_t s = 0;
    for (int i = lo; i < hi; ++i) s += in[i];
    part[tid] = s;
    __syncthreads();
    for (int off = 1; off < 256; off <<= 1) {
        uint_t v = (tid >= off) ? part[tid - off] : 0u;
        __syncthreads();
        part[tid] += v;
        __syncthreads();
    }
    uint_t run = part[tid] - s;
    for (int i = lo; i < hi; ++i) {
        out[i] = run;
        if (out2) out2[i] = run;
        run += in[i];
    }
    if (tid == 255) out[n] = run;
}

#define TPB 4096
// K2b (FUSED): both bucket scatters in one kernel. ei read from HBM ONCE (the
// A-scatter pass re-reads the block's 32 KB ei segment from L2); the A and C
// scatter latency chains interleave in the same waves -> 2x memory-level
// parallelism at the same occupancy (round-11: each kernel alone sat at
// VALUBusy ~2%, latency-bound). LDS 58.8 KB -> 2 blocks/CU.
__global__ void bucket_place_AC(const int* __restrict__ ei, const float* __restrict__ ea,
                                uint_t* __restrict__ bcurA, uint_t* __restrict__ bcurC,
                                uint4* __restrict__ pk4, uint_t* __restrict__ pkC) {
    __shared__ uint_t histA[NBKT2], gbaseA[NBKT2], curA[NBKT2];   // 18.8 KB
    __shared__ uint_t pkst[TPB];                                  // 16 KB C-keys
    __shared__ uint_t gpk[TPB];                                   // 16 KB reordered
    __shared__ uint_t histC[NBKT], lbaseC[NBKT], gbaseC[NBKT], curC[NBKT];
    __shared__ uint_t part[1024];
    int tid = threadIdx.x;
    int t0 = blockIdx.x * TPB;
    int nt = EE - t0; if (nt > TPB) nt = TPB;
    for (int i = tid; i < NBKT2; i += 1024) { histA[i] = 0; curA[i] = 0; }
    for (int i = tid; i < NBKT; i += 1024) { histC[i] = 0; curC[i] = 0; }
    __syncthreads();
    for (int i = tid; i < nt; i += 1024) {
        int e = t0 + i;
        uint_t u = (uint_t)ei[e];
        uint_t v = (uint_t)ei[EE + e];
        atomicAdd(&histA[(u / 12500u) * 196u + (v >> 9)], 1u);
        uint_t w = ((u >> 2) << 15) | (v >> 2);
        pkst[i] = w;
        atomicAdd(&histC[w >> 22], 1u);
    }
    __syncthreads();
    for (int b = tid; b < NBKT2; b += 1024) {
        uint_t h = histA[b];
        if (h) gbaseA[b] = atomicAdd(&bcurA[b], h);
    }
    uint_t h = (tid < NBKT) ? histC[tid] : 0u;
    if (tid < NBKT) gbaseC[tid] = atomicAdd(&bcurC[tid], h);
    part[tid] = h;
    __syncthreads();
    for (int off = 1; off < 1024; off <<= 1) {
        uint_t v = (tid >= off) ? part[tid - off] : 0u;
        __syncthreads();
        part[tid] += v;
        __syncthreads();
    }
    if (tid < NBKT) lbaseC[tid] = part[tid] - h;
    __syncthreads();
    // C-side LDS reorder, then grouped global write
    for (int i = tid; i < nt; i += 1024) {
        uint_t w = pkst[i];
        uint_t b = w >> 22;
        uint_t r = lbaseC[b] + atomicAdd(&curC[b], 1u);
        gpk[r] = w;
    }
    __syncthreads();
    for (int r = tid; r < nt; r += 1024) {
        uint_t w = gpk[r];
        uint_t b = w >> 22;
        pkC[gbaseC[b] + ((uint_t)r - lbaseC[b])] = w;
    }
    // A-side scatter: ei re-read is L2-hot; ea read coalesced once
    for (int i = tid; i < nt; i += 1024) {
        int e = t0 + i;
        uint_t u = (uint_t)ei[e];
        uint_t v = (uint_t)ei[EE + e];
        uint_t b = (u / 12500u) * 196u + (v >> 9);
        uint_t r = gbaseA[b] + atomicAdd(&curA[b], 1u);
        uint4 p;
        p.x = (((v >> 2) & 127u) << 17) | u;
        p.y = __float_as_uint(ea[(size_t)e * 3 + 0]);
        p.z = __float_as_uint(ea[(size_t)e * 3 + 1]);
        p.w = __float_as_uint(ea[(size_t)e * 3 + 2]);
        pk4[r] = p;
    }
}

// K2c: in-LDS counting sort of each (slice, dst-coarse) bucket by cluster-local id;
// sorted KEYS (.x) written to pkW. ea sums per cluster via LDS FLOAT ATOMICS keyed
// by the cluster id in the key (order-independent — round-8's sorted-range read of
// unsorted st[] was the absmax=41.9 bug).
__global__ void bucket_sort_A2(const uint_t* __restrict__ bbA2, const uint4* __restrict__ pk4,
                               uint_t* __restrict__ pkW, uint_t* __restrict__ paggw,
                               uint_t* __restrict__ offs2) {
    __shared__ uint4 st[2048];                      // 32 KB payload staging
    __shared__ uint_t hist[128], base2[128], cur[128];
    __shared__ float eacc0[128], eacc1[128], eacc2[128];
    __shared__ uint_t part[256];
    int tid = threadIdx.x, bk = blockIdx.x;
    uint_t s = bbA2[bk], epos = bbA2[bk + 1];
    int n = (int)(epos - s);
    if (n > 2048) n = 2048;   // statistically unreachable; guards LDS bounds
    if (tid < 128) {
        hist[tid] = 0; cur[tid] = 0;
        eacc0[tid] = 0.f; eacc1[tid] = 0.f; eacc2[tid] = 0.f;
    }
    for (int i = tid; i < n; i += 256) st[i] = pk4[s + i];
    __syncthreads();
    for (int i = tid; i < n; i += 256) {
        uint4 p = st[i];
        uint_t d = p.x >> 17;
        atomicAdd(&hist[d], 1u);
        atomicAdd(&eacc0[d], __uint_as_float(p.y));
        atomicAdd(&eacc1[d], __uint_as_float(p.z));
        atomicAdd(&eacc2[d], __uint_as_float(p.w));
    }
    __syncthreads();
    uint_t h = (tid < 128) ? hist[tid] : 0u;
    part[tid] = h;
    __syncthreads();
    for (int off = 1; off < 256; off <<= 1) {
        uint_t v = (tid >= off) ? part[tid - off] : 0u;
        __syncthreads();
        part[tid] += v;
        __syncthreads();
    }
    int sl = bk / 196, q = bk - sl * 196;
    if (tid < 128) {
        base2[tid] = part[tid] - h;
        int c = q * 128 + tid;
        if (c < CC) {
            uint_t kk = (uint_t)sl * CC + (uint_t)c;
            offs2[kk] = s + base2[tid];
            paggw[(size_t)kk * 66 + 64] = f2bf(eacc0[tid]) | (f2bf(eacc1[tid]) << 16);
            paggw[(size_t)kk * 66 + 65] = f2bf(eacc2[tid]);   // slot 131 = 0
        }
    }
    if (bk == 0 && tid == 0) offs2[8 * CC] = EE;
    __syncthreads();
    for (int i = tid; i < n; i += 256) {
        uint4 p = st[i];
        uint_t d = p.x >> 17;
        uint_t r = base2[d] + atomicAdd(&cur[d], 1u);
        pkW[s + r] = p.x;
    }
}

// K2c': counting-sort each C-bucket by 5-bit sub key ((u>>2)&31), in place, so the
// dedupe kernels read ONLY their own ~256-entry segment.
__global__ void bucket_sort_C(const uint_t* __restrict__ bbC, uint_t* __restrict__ pkC,
                              uint_t* __restrict__ csub) {
    __shared__ uint_t st[8960];                     // 35.8 KB (bucket mean 8192, +8.5 sigma)
    __shared__ uint_t hist[32], base2[32], cur[32];
    __shared__ uint_t part[256];
    int tid = threadIdx.x, bk = blockIdx.x;
    uint_t s = bbC[bk], epos = bbC[bk + 1];
    int n = (int)(epos - s);
    if (n > 8960) n = 8960;
    if (tid < 32) { hist[tid] = 0; cur[tid] = 0; }
    for (int i = tid; i < n; i += 256) st[i] = pkC[s + i];
    __syncthreads();
    for (int i = tid; i < n; i += 256) atomicAdd(&hist[(st[i] >> 17) & 31u], 1u);
    __syncthreads();
    uint_t h = (tid < 32) ? hist[tid] : 0u;
    part[tid] = h;
    __syncthreads();
    for (int off = 1; off < 256; off <<= 1) {
        uint_t v = (tid >= off) ? part[tid - off] : 0u;
        __syncthreads();
        part[tid] += v;
        __syncthreads();
    }
    if (tid < 32) {
        base2[tid] = part[tid] - h;
        csub[bk * 32 + tid] = s + base2[tid];
    }
    if (bk == 0 && tid == 0) csub[NSEG] = EE;
    __syncthreads();
    for (int i = tid; i < n; i += 256) {
        uint_t w = st[i];
        uint_t d = (w >> 17) & 31u;
        uint_t r = base2[d] + atomicAdd(&cur[d], 1u);
        pkC[s + r] = w;
    }
}

// K3: per cluster: new_pos + new_batch straight to out (enc_emit reads out[O_POS]).
__global__ void cluster_pass(const float* __restrict__ pos, const int* __restrict__ batch,
                             float* __restrict__ out) {
    int c = blockIdx.x * 256 + threadIdx.x;
    if (c >= CC) return;
    float px = 0.f, py = 0.f, pz = 0.f;
    for (int j = 0; j < 4; ++j) {
        int n = c * 4 + j;
        px += pos[n * 3 + 0];
        py += pos[n * 3 + 1];
        pz += pos[n * 3 + 2];
    }
    px *= 0.25f; py *= 0.25f; pz *= 0.25f;
    out[O_POS + c * 3 + 0] = px;
    out[O_POS + c * 3 + 1] = py;
    out[O_POS + c * 3 + 2] = pz;
    int b = batch[c * 4];
    b = max(b, batch[c * 4 + 1]);
    b = max(b, batch[c * 4 + 2]);
    b = max(b, batch[c * 4 + 3]);
    out[O_BATCH + c] = (float)b;
}

// K2d: XCD-affine x-gather reduce. One wave per (slice s, cluster c) segment;
// s = blockIdx&7 pins x-slice s (3.2 MB) to one XCD's L2 (round-5 verified).
// Unroll-4, batched consecutive key loads (s_load_dwordx4). i-ascending order.
__global__ void cluster_reduce4(const uint_t* __restrict__ offs2, const uint_t* __restrict__ pkW,
                                const uint_t* __restrict__ xb, uint_t* __restrict__ paggw) {
    int tid = threadIdx.x;
    int lane = tid & 63;
    int s = blockIdx.x & 7;
    int c = (blockIdx.x >> 3) * 4 + (tid >> 6);     // 0..24999
    uint_t kk = (uint_t)s * CC + (uint_t)c;
    uint_t start = (uint_t)__builtin_amdgcn_readfirstlane((int)offs2[kk]);
    uint_t end   = (uint_t)__builtin_amdgcn_readfirstlane((int)offs2[kk + 1]);
    const uint_t* xl = xb + lane;
    float a0 = 0.f, a1 = 0.f;
    uint_t i = start;
    for (; i + 4u <= end; i += 4u) {
        uint_t w0 = pkW[i + 0u];                    // uniform, consecutive -> s_load_dwordx4
        uint_t w1 = pkW[i + 1u];
        uint_t w2 = pkW[i + 2u];
        uint_t w3 = pkW[i + 3u];
        uint_t x0 = xl[(size_t)(w0 & 0x1FFFFu) * 64u];   // 4 independent 256 B row loads
        uint_t x1 = xl[(size_t)(w1 & 0x1FFFFu) * 64u];
        uint_t x2 = xl[(size_t)(w2 & 0x1FFFFu) * 64u];
        uint_t x3 = xl[(size_t)(w3 & 0x1FFFFu) * 64u];
        a0 += bf2f((ushort_t)(x0 & 0xffffu)); a1 += bf2f((ushort_t)(x0 >> 16));
        a0 += bf2f((ushort_t)(x1 & 0xffffu)); a1 += bf2f((ushort_t)(x1 >> 16));
        a0 += bf2f((ushort_t)(x2 & 0xffffu)); a1 += bf2f((ushort_t)(x2 >> 16));
        a0 += bf2f((ushort_t)(x3 & 0xffffu)); a1 += bf2f((ushort_t)(x3 >> 16));
    }
    for (; i < end; ++i) {
        uint_t wj = pkW[i];
        uint_t xv = xl[(size_t)(wj & 0x1FFFFu) * 64u];
        a0 += bf2f((ushort_t)(xv & 0xffffu));
        a1 += bf2f((ushort_t)(xv >> 16));
    }
    paggw[(size_t)kk * 66 + lane] = f2bf(a0) | (f2bf(a1) << 16);
}

// K4: x_new[c][o] = 0.25 * sum_{j<131} (sum_s pagg[s][c][j]) * M1[j][o].
// agg_merge FUSED into the staging loop (slice order s=0..7 preserved; staged
// value is the unrounded f32 sum — one fewer bf16 rounding than before).
#define GEMM_CPB 32   // clusters per block = 4 iterations of 8
__global__ void gemm_tiled(const uint_t* __restrict__ paggw, const ushort_t* __restrict__ m1b,
                           float* __restrict__ out) {
    __shared__ ushort_t m1s[131 * 128];            // 33.5 KB bf16
    __shared__ __align__(16) float srowT[132][8];  // 4.2 KB, [j][cluster-in-group]
    int tid = threadIdx.x;
    {
        const uint_t* m1w = (const uint_t*)m1b;
        uint_t* m1sw = (uint_t*)m1s;
        for (int i = tid; i < 131 * 64; i += 256) m1sw[i] = m1w[i];
    }
    int o = tid & 127, half = tid >> 7;
    int c0b = blockIdx.x * GEMM_CPB;
    for (int it = 0; it < GEMM_CPB / 8; ++it) {
        int c0 = c0b + it * 8;
        __syncthreads();   // previous-iteration readers done before overwrite
        for (int i = tid; i < 528; i += 256) {
            int cg = i / 66, rem = i - cg * 66;
            int c = c0 + cg;
            float lo = 0.f, hi = 0.f;
            if (c < CC) {
                #pragma unroll
                for (int s = 0; s < 8; ++s) {
                    uint_t w = paggw[((size_t)s * 25000u + (uint_t)c) * 66 + rem];
                    lo += bf2f((ushort_t)(w & 0xffffu));
                    hi += bf2f((ushort_t)(w >> 16));
                }
            }
            srowT[rem * 2][cg]     = lo;
            srowT[rem * 2 + 1][cg] = hi;
        }
        __syncthreads();   // also covers m1s staging on it==0
        float acc0 = 0.f, acc1 = 0.f, acc2 = 0.f, acc3 = 0.f;
        #pragma unroll 4
        for (int j = 0; j < 131; ++j) {
            float m = bf2f(m1s[j * 128 + o]);
            float4 s = *(const float4*)&srowT[j][half * 4];  // broadcast within wave
            acc0 += s.x * m;
            acc1 += s.y * m;
            acc2 += s.z * m;
            acc3 += s.w * m;
        }
        int cb = c0 + half * 4;
        if (cb + 0 < CC) out[O_XNEW + (size_t)(cb + 0) * 128 + o] = 0.25f * acc0;
        if (cb + 1 < CC) out[O_XNEW + (size_t)(cb + 1) * 128 + o] = 0.25f * acc1;
        if (cb + 2 < CC) out[O_XNEW + (size_t)(cb + 2) * 128 + o] = 0.25f * acc2;
        if (cb + 3 < CC) out[O_XNEW + (size_t)(cb + 3) * 128 + o] = 0.25f * acc3;
    }
}

// K6a: per-segment dedupe: read OWN ~256-entry segment, 12.5 KB LDS bitmap
// (4 u-clusters x 25000 v bits), block scan, emit deduped keys (le, rank-dense)
// to kbuf[bid*KCAP] + count. Bitmap built ONCE (emit kernel reads keys, not pkC).
__global__ void enc_count(const uint_t* __restrict__ csub, const uint_t* __restrict__ pkC,
                          uint_t* __restrict__ bcnt, uint_t* __restrict__ kbuf) {
    __shared__ uint_t bmp[3125];
    __shared__ uint_t sh[256];
    int tid = threadIdx.x, bid = blockIdx.x;
    uint_t s = csub[bid], epos = csub[bid + 1];
    int n = (int)(epos - s);
    for (int i = tid; i < 3125; i += 256) bmp[i] = 0;
    __syncthreads();
    for (int i = tid; i < n; i += 256) {
        uint_t w = pkC[s + i];
        uint_t le = ((w >> 15) & 3u) * 25000u + (w & 32767u);
        atomicOr(&bmp[le >> 5], 1u << (le & 31u));
    }
    __syncthreads();
    int lo = tid * 13, hi = lo + 13;
    if (lo > 3125) lo = 3125;
    if (hi > 3125) hi = 3125;
    uint_t mine = 0;
    for (int i = lo; i < hi; ++i) mine += __popc(bmp[i]);
    sh[tid] = mine;
    __syncthreads();
    for (int off = 1; off < 256; off <<= 1) {
        uint_t v = (tid >= off) ? sh[tid - off] : 0u;
        __syncthreads();
        sh[tid] += v;
        __syncthreads();
    }
    uint_t r = sh[tid] - mine;
    uint_t kb = (uint_t)bid * KCAP;
    for (int i = lo; i < hi; ++i) {
        uint_t bits = bmp[i];
        while (bits) {
            int b = __builtin_ctz(bits);
            bits &= bits - 1u;
            if (r < KCAP) kbuf[kb + r] = (uint_t)i * 32u + (uint_t)b;
            r++;
        }
    }
    if (tid == 255) bcnt[bid] = min(sh[255], (uint_t)KCAP);
}

// K6b: decode dense keys, write u/v COALESCED + attrs (np gathers are L2-resident).
// Global order: bid asc (= u-group asc), key asc within (= (u&3, v) asc) ->
// ascending enc, identical to jnp.unique output order.
__global__ void enc_emit(const uint_t* __restrict__ ebase, const uint_t* __restrict__ kbuf,
                         float* __restrict__ out) {
    int tid = threadIdx.x, bid = blockIdx.x;
    uint_t g0 = ebase[bid], g1 = ebase[bid + 1];
    int cnt = (int)(g1 - g0);
    const float* np = out + O_POS;
    uint_t ubase = ((uint_t)(bid >> 5)) * 128u + ((uint_t)(bid & 31)) * 4u;
    uint_t kb = (uint_t)bid * KCAP;
    for (int r = tid; r < cnt; r += 256) {
        uint_t le = kbuf[kb + r];
        uint_t uo = le / 25000u;
        uint_t v = le - uo * 25000u;
        uint_t u = ubase + uo;
        uint_t rank = g0 + (uint_t)r;
        out[O_EI + rank] = (float)u;
        out[O_EI + EE + rank] = (float)v;
        out[O_ATTR + (size_t)rank * 3 + 0] = np[v * 3 + 0] - np[u * 3 + 0];
        out[O_ATTR + (size_t)rank * 3 + 1] = np[v * 3 + 1] - np[u * 3 + 1];
        out[O_ATTR + (size_t)rank * 3 + 2] = np[v * 3 + 2] - np[u * 3 + 2];
    }
}

extern "C" void kernel_launch(void* const* d_in, const int* in_sizes, int n_in,
                              void* d_out, int out_size, void* d_ws, size_t ws_size,
                              hipStream_t stream) {
    const float* x     = (const float*)d_in[0];
    const float* pos   = (const float*)d_in[1];
    const int*   ei    = (const int*)d_in[2];
    const float* ea    = (const float*)d_in[3];
    const int*   batch = (const int*)d_in[4];
    const float* Wconv = (const float*)d_in[5];
    const float* Wedge = (const float*)d_in[6];
    // d_in[7] = D_bloom: dead (bloom_pos never reaches an output)
    const float* Wg    = (const float*)d_in[8];
    // d_in[9] = W_gattr: contribution cancels exactly within each cluster

    float*  out = (float*)d_out;
    uint_t* ws  = (uint_t*)d_ws;

    if (ws_size < (size_t)WS_WORDS * 4) return;

    ushort_t* m1b    = (ushort_t*)(ws + W_M1B);
    uint_t*   pkW    = ws + W_AGGB;             // sorted keys
    uint_t*   paggw  = ws + W_PAGG;
    uint4*    pk4    = (uint4*)(ws + W_PKA4);
    uint_t*   pkC    = ws + W_PKC;
    uint_t*   offs2  = ws + W_OFFS2;
    uint_t*   bhA2   = ws + W_BHA2;
    uint_t*   bhC    = ws + W_BHC;
    uint_t*   bbA2   = ws + W_BBA2;
    uint_t*   bcurA2 = ws + W_BCURA2;
    uint_t*   bbC    = ws + W_BBC;
    uint_t*   bcurC  = ws + W_BCURC;
    uint_t*   xb     = (uint_t*)(out + O_EI);   // 6.4M-word bf16-x staging in out region
    // dead-region reuse (valid after bucket_sort_A2 / gemm_tiled):
    uint_t*   csub   = ws + W_PKA4;             // u32 [NSEG+1]
    uint_t*   bcnt2  = ws + W_PKA4 + 8192u;     // u32 [NSEG]
    uint_t*   ebase2 = ws + W_PKA4 + 16384u;    // u32 [NSEG+1]
    uint_t*   kbuf   = ws + W_PAGG;             // u32 [NSEG*KCAP] = 6.42M <= 13.2M

    hipMemsetAsync(bhA2, 0, (size_t)(NBKT2 + NBKT) * 4, stream);   // bhA2 + bhC contiguous

    xpack<<<dim3(12500), dim3(256), 0, stream>>>((const float4*)x, (uint2*)xb);
    build_m1f<<<dim3(131), dim3(128), 0, stream>>>(Wconv, Wedge, Wg, m1b);
    edge_hist2<<<dim3(256), dim3(1024), 0, stream>>>(ei, bhA2, bhC);
    scan_small<<<dim3(1), dim3(256), 0, stream>>>(bhA2, bbA2, bcurA2, NBKT2);
    scan_small<<<dim3(1), dim3(256), 0, stream>>>(bhC, bbC, bcurC, NBKT);
    bucket_place_AC<<<dim3((EE + TPB - 1) / TPB), dim3(1024), 0, stream>>>(ei, ea, bcurA2, bcurC, pk4, pkC);
    bucket_sort_A2<<<dim3(NBKT2), dim3(256), 0, stream>>>(bbA2, pk4, pkW, paggw, offs2);
    cluster_pass<<<dim3(98), dim3(256), 0, stream>>>(pos, batch, out);
    cluster_reduce4<<<dim3(50000), dim3(256), 0, stream>>>(offs2, pkW, xb, paggw);
    gemm_tiled<<<dim3((CC + GEMM_CPB - 1) / GEMM_CPB), dim3(256), 0, stream>>>(paggw, m1b, out);
    // x_bf16 staging no longer needed: zero the EI/ATTR region (incl. padding tail)
    hipMemsetAsync((char*)d_out + (size_t)O_EI * 4, 0, (size_t)(3200000 + 4800000) * 4, stream);
    bucket_sort_C<<<dim3(NBKT), dim3(256), 0, stream>>>(bbC, pkC, csub);
    enc_count<<<dim3(NSEG), dim3(256), 0, stream>>>(csub, pkC, bcnt2, kbuf);
    scan_small<<<dim3(1), dim3(256), 0, stream>>>(bcnt2, ebase2, (uint_t*)0, NSEG);
    enc_emit<<<dim3(NSEG), dim3(256), 0, stream>>>(ebase2, kbuf, out);
}

// Round 13
// 431.014 us; speedup vs baseline: 1.1670x; 1.0013x over previous
//
#include <hip/hip_runtime.h>
#include <hip/hip_bf16.h>
#include <stdint.h>

typedef unsigned int uint_t;
typedef unsigned short ushort_t;

#define NN 100000
#define EE 1600000
#define CC 25000
#define DINTER 144
#define NBKT 196          // C-side coarse buckets: src cluster >> 7
#define NBKT2 1568        // A-side buckets: (src_node/12500)*196 + (dst_node>>9)
#define NSEG 6272         // dedupe segments: 196 buckets * 32 subs (4 u-clusters each)
#define KCAP 1024         // keys per segment cap (mean 256, sigma 16 -> +48 sigma)

// ---- ws layout in 32-bit words (total 92.27 MB, proven) ----
#define W_M1B      0u         // u16 [131*128] bf16 m1 = 8384 words
#define W_AGGB     8384u      // pkW sorted keys region (u32 [1,600,000] fits in 1,650,000)
#define W_PAGG     1658384u   // bf16[8][25000*132] = 13,200,000 words (kbuf reuse after gemm)
#define W_PKA4     14858384u  // uint4[1,600,000] = 6,400,000 words (csub/bcnt/ebase reuse after sort)
#define W_PKC      21258384u  // u32 [1600000]
#define W_OFFS2    22858384u  // u32 [200001]  per-(slice,cluster) segment offsets
#define W_BHA2     23058385u  // u32 [1568]
#define W_BHC      23059953u  // u32 [196]   (adjacent to BHA2: one memset of 1764)
#define W_BBA2     23060149u  // u32 [1569]
#define W_BCURA2   23061718u  // u32 [1568]
#define W_BBC      23063286u  // u32 [197]
#define W_BCURC    23063483u  // u32 [196]
#define WS_WORDS   23066816u

// ---- out layout in FLOAT32 elements (total 11,300,000) ----
#define O_XNEW  0u
#define O_POS   3200000u
#define O_EI    3275000u
#define O_ATTR  6475000u
#define O_BATCH 11275000u
// x_bf16 staging: first 6.4M words of the O_EI region (re-zeroed before enc_count/emit)
// new_pos f32[25000*3] lives at out[O_POS] and is read back by enc_emit.

static __device__ __forceinline__ uint_t f2bf(float f) {
    union { float f; uint_t i; } v; v.f = f;
    uint_t x = v.i;
    return (x + 0x7fffu + ((x >> 16) & 1u)) >> 16;  // RNE
}
static __device__ __forceinline__ float bf2f(ushort_t u) {
    union { uint_t i; float f; } v; v.i = ((uint_t)u) << 16; return v.f;
}

// K0: pack x (f32) -> bf16x2 words into the output-staging region.
__global__ void xpack(const float4* __restrict__ x4, uint2* __restrict__ xb2) {
    int i = blockIdx.x * 256 + threadIdx.x;
    if (i >= NN * 32) return;            // 12.8M floats / 4
    float4 v = x4[i];
    uint2 r;
    r.x = f2bf(v.x) | (f2bf(v.y) << 16);
    r.y = f2bf(v.z) | (f2bf(v.w) << 16);
    xb2[i] = r;
}

// K1: M1[j][o] = sum_f Wrow_j[f] * Wg[f][o], emitted directly as bf16.
__global__ void build_m1f(const float* __restrict__ Wconv,
                          const float* __restrict__ Wedge,
                          const float* __restrict__ Wg,
                          ushort_t* __restrict__ m1b) {
    int j = blockIdx.x;   // 0..130
    int o = threadIdx.x;  // 0..127
    const float* wrow = (j < 128) ? (Wconv + j * DINTER + 16)
                                  : (Wedge + (j - 128) * DINTER + 16);
    float acc = 0.f;
    for (int f = 0; f < 128; ++f)
        acc += wrow[f] * Wg[f * 128 + o];
    m1b[j * 128 + o] = (ushort_t)f2bf(acc);
}

// K2a: fused coarse histograms (LDS-aggregated). 1024-thread blocks.
__global__ void edge_hist2(const int* __restrict__ ei,
                           uint_t* __restrict__ bhA2, uint_t* __restrict__ bhC) {
    __shared__ uint_t hA[NBKT2], hC[NBKT];
    int tid = threadIdx.x;
    for (int i = tid; i < NBKT2; i += 1024) hA[i] = 0;
    for (int i = tid; i < NBKT; i += 1024) hC[i] = 0;
    __syncthreads();
    for (int e = blockIdx.x * 1024 + tid; e < EE; e += 256 * 1024) {
        uint_t u = (uint_t)ei[e];
        uint_t v = (uint_t)ei[EE + e];
        atomicAdd(&hA[(u / 12500u) * 196u + (v >> 9)], 1u);
        atomicAdd(&hC[u >> 9], 1u);
    }
    __syncthreads();
    for (int i = tid; i < NBKT2; i += 1024) if (hA[i]) atomicAdd(&bhA2[i], hA[i]);
    for (int i = tid; i < NBKT; i += 1024)  if (hC[i]) atomicAdd(&bhC[i], hC[i]);
}

// Single-block exclusive scan. out[0..n] (out[n]=total), optional copy out2[0..n-1].
__global__ void scan_small(const uint_t* __restrict__ in, uint_t* __restrict__ out,
                           uint_t* __restrict__ out2, int n) {
    __shared__ uint_t part[256];
    int tid = threadIdx.x;
    int per = (n + 255) >> 8;
    int lo = tid * per;
    int hi = lo + per; if (hi > n) hi = n;
    if (lo > n) lo = n;
    uint_t s = 0;
    for (int i = lo; i < hi; ++i) s += in[i];
    part[tid] = s;
    __syncthreads();
    for (int off = 1; off < 256; off <<= 1) {
        uint_t v = (tid >= off) ? part[tid - off] : 0u;
        __syncthreads();
        part[tid] += v;
        __syncthreads();
    }
    uint_t run = part[tid] - s;
    for (int i = lo; i < hi; ++i) {
        out[i] = run;
        if (out2) out2[i] = run;
        run += in[i];
    }
    if (tid == 255) out[n] = run;
}

#define TPB 4096
// K2b (FUSED): both bucket scatters in one kernel. ei read from HBM ONCE (the
// A-scatter pass re-reads the block's 32 KB ei segment from L2); the A and C
// scatter latency chains interleave in the same waves. LDS 58.8 KB -> 2 blocks/CU.
__global__ void bucket_place_AC(const int* __restrict__ ei, const float* __restrict__ ea,
                                uint_t* __restrict__ bcurA, uint_t* __restrict__ bcurC,
                                uint4* __restrict__ pk4, uint_t* __restrict__ pkC) {
    __shared__ uint_t histA[NBKT2], gbaseA[NBKT2], curA[NBKT2];   // 18.8 KB
    __shared__ uint_t pkst[TPB];                                  // 16 KB C-keys
    __shared__ uint_t gpk[TPB];                                   // 16 KB reordered
    __shared__ uint_t histC[NBKT], lbaseC[NBKT], gbaseC[NBKT], curC[NBKT];
    __shared__ uint_t part[1024];
    int tid = threadIdx.x;
    int t0 = blockIdx.x * TPB;
    int nt = EE - t0; if (nt > TPB) nt = TPB;
    for (int i = tid; i < NBKT2; i += 1024) { histA[i] = 0; curA[i] = 0; }
    for (int i = tid; i < NBKT; i += 1024) { histC[i] = 0; curC[i] = 0; }
    __syncthreads();
    for (int i = tid; i < nt; i += 1024) {
        int e = t0 + i;
        uint_t u = (uint_t)ei[e];
        uint_t v = (uint_t)ei[EE + e];
        atomicAdd(&histA[(u / 12500u) * 196u + (v >> 9)], 1u);
        uint_t w = ((u >> 2) << 15) | (v >> 2);
        pkst[i] = w;
        atomicAdd(&histC[w >> 22], 1u);
    }
    __syncthreads();
    for (int b = tid; b < NBKT2; b += 1024) {
        uint_t h = histA[b];
        if (h) gbaseA[b] = atomicAdd(&bcurA[b], h);
    }
    uint_t h = (tid < NBKT) ? histC[tid] : 0u;
    if (tid < NBKT) gbaseC[tid] = atomicAdd(&bcurC[tid], h);
    part[tid] = h;
    __syncthreads();
    for (int off = 1; off < 1024; off <<= 1) {
        uint_t v = (tid >= off) ? part[tid - off] : 0u;
        __syncthreads();
        part[tid] += v;
        __syncthreads();
    }
    if (tid < NBKT) lbaseC[tid] = part[tid] - h;
    __syncthreads();
    // C-side LDS reorder, then grouped global write
    for (int i = tid; i < nt; i += 1024) {
        uint_t w = pkst[i];
        uint_t b = w >> 22;
        uint_t r = lbaseC[b] + atomicAdd(&curC[b], 1u);
        gpk[r] = w;
    }
    __syncthreads();
    for (int r = tid; r < nt; r += 1024) {
        uint_t w = gpk[r];
        uint_t b = w >> 22;
        pkC[gbaseC[b] + ((uint_t)r - lbaseC[b])] = w;
    }
    // A-side scatter: ei re-read is L2-hot; ea read coalesced once
    for (int i = tid; i < nt; i += 1024) {
        int e = t0 + i;
        uint_t u = (uint_t)ei[e];
        uint_t v = (uint_t)ei[EE + e];
        uint_t b = (u / 12500u) * 196u + (v >> 9);
        uint_t r = gbaseA[b] + atomicAdd(&curA[b], 1u);
        uint4 p;
        p.x = (((v >> 2) & 127u) << 17) | u;
        p.y = __float_as_uint(ea[(size_t)e * 3 + 0]);
        p.z = __float_as_uint(ea[(size_t)e * 3 + 1]);
        p.w = __float_as_uint(ea[(size_t)e * 3 + 2]);
        pk4[r] = p;
    }
}

// K2c: in-LDS counting sort of each (slice, dst-coarse) bucket by cluster-local id;
// sorted KEYS (.x) written to pkW. ea sums per cluster via LDS FLOAT ATOMICS keyed
// by the cluster id in the key (order-independent — round-8's sorted-range read of
// unsorted st[] was the absmax=41.9 bug).
__global__ void bucket_sort_A2(const uint_t* __restrict__ bbA2, const uint4* __restrict__ pk4,
                               uint_t* __restrict__ pkW, uint_t* __restrict__ paggw,
                               uint_t* __restrict__ offs2) {
    __shared__ uint4 st[2048];                      // 32 KB payload staging
    __shared__ uint_t hist[128], base2[128], cur[128];
    __shared__ float eacc0[128], eacc1[128], eacc2[128];
    __shared__ uint_t part[256];
    int tid = threadIdx.x, bk = blockIdx.x;
    uint_t s = bbA2[bk], epos = bbA2[bk + 1];
    int n = (int)(epos - s);
    if (n > 2048) n = 2048;   // statistically unreachable; guards LDS bounds
    if (tid < 128) {
        hist[tid] = 0; cur[tid] = 0;
        eacc0[tid] = 0.f; eacc1[tid] = 0.f; eacc2[tid] = 0.f;
    }
    for (int i = tid; i < n; i += 256) st[i] = pk4[s + i];
    __syncthreads();
    for (int i = tid; i < n; i += 256) {
        uint4 p = st[i];
        uint_t d = p.x >> 17;
        atomicAdd(&hist[d], 1u);
        atomicAdd(&eacc0[d], __uint_as_float(p.y));
        atomicAdd(&eacc1[d], __uint_as_float(p.z));
        atomicAdd(&eacc2[d], __uint_as_float(p.w));
    }
    __syncthreads();
    uint_t h = (tid < 128) ? hist[tid] : 0u;
    part[tid] = h;
    __syncthreads();
    for (int off = 1; off < 256; off <<= 1) {
        uint_t v = (tid >= off) ? part[tid - off] : 0u;
        __syncthreads();
        part[tid] += v;
        __syncthreads();
    }
    int sl = bk / 196, q = bk - sl * 196;
    if (tid < 128) {
        base2[tid] = part[tid] - h;
        int c = q * 128 + tid;
        if (c < CC) {
            uint_t kk = (uint_t)sl * CC + (uint_t)c;
            offs2[kk] = s + base2[tid];
            paggw[(size_t)kk * 66 + 64] = f2bf(eacc0[tid]) | (f2bf(eacc1[tid]) << 16);
            paggw[(size_t)kk * 66 + 65] = f2bf(eacc2[tid]);   // slot 131 = 0
        }
    }
    if (bk == 0 && tid == 0) offs2[8 * CC] = EE;
    __syncthreads();
    for (int i = tid; i < n; i += 256) {
        uint4 p = st[i];
        uint_t d = p.x >> 17;
        uint_t r = base2[d] + atomicAdd(&cur[d], 1u);
        pkW[s + r] = p.x;
    }
}

// K2c': counting-sort each C-bucket by 5-bit sub key ((u>>2)&31), in place, so the
// dedupe kernels read ONLY their own ~256-entry segment.
__global__ void bucket_sort_C(const uint_t* __restrict__ bbC, uint_t* __restrict__ pkC,
                              uint_t* __restrict__ csub) {
    __shared__ uint_t st[8960];                     // 35.8 KB (bucket mean 8192, +8.5 sigma)
    __shared__ uint_t hist[32], base2[32], cur[32];
    __shared__ uint_t part[256];
    int tid = threadIdx.x, bk = blockIdx.x;
    uint_t s = bbC[bk], epos = bbC[bk + 1];
    int n = (int)(epos - s);
    if (n > 8960) n = 8960;
    if (tid < 32) { hist[tid] = 0; cur[tid] = 0; }
    for (int i = tid; i < n; i += 256) st[i] = pkC[s + i];
    __syncthreads();
    for (int i = tid; i < n; i += 256) atomicAdd(&hist[(st[i] >> 17) & 31u], 1u);
    __syncthreads();
    uint_t h = (tid < 32) ? hist[tid] : 0u;
    part[tid] = h;
    __syncthreads();
    for (int off = 1; off < 256; off <<= 1) {
        uint_t v = (tid >= off) ? part[tid - off] : 0u;
        __syncthreads();
        part[tid] += v;
        __syncthreads();
    }
    if (tid < 32) {
        base2[tid] = part[tid] - h;
        csub[bk * 32 + tid] = s + base2[tid];
    }
    if (bk == 0 && tid == 0) csub[NSEG] = EE;
    __syncthreads();
    for (int i = tid; i < n; i += 256) {
        uint_t w = st[i];
        uint_t d = (w >> 17) & 31u;
        uint_t r = base2[d] + atomicAdd(&cur[d], 1u);
        pkC[s + r] = w;
    }
}

// K3: per cluster: new_pos + new_batch straight to out (enc_emit reads out[O_POS]).
__global__ void cluster_pass(const float* __restrict__ pos, const int* __restrict__ batch,
                             float* __restrict__ out) {
    int c = blockIdx.x * 256 + threadIdx.x;
    if (c >= CC) return;
    float px = 0.f, py = 0.f, pz = 0.f;
    for (int j = 0; j < 4; ++j) {
        int n = c * 4 + j;
        px += pos[n * 3 + 0];
        py += pos[n * 3 + 1];
        pz += pos[n * 3 + 2];
    }
    px *= 0.25f; py *= 0.25f; pz *= 0.25f;
    out[O_POS + c * 3 + 0] = px;
    out[O_POS + c * 3 + 1] = py;
    out[O_POS + c * 3 + 2] = pz;
    int b = batch[c * 4];
    b = max(b, batch[c * 4 + 1]);
    b = max(b, batch[c * 4 + 2]);
    b = max(b, batch[c * 4 + 3]);
    out[O_BATCH + c] = (float)b;
}

// K2d: XCD-affine x-gather reduce. One wave per (slice s, cluster c) segment;
// s = blockIdx&7 pins x-slice s (3.2 MB) to one XCD's L2 (round-5 verified).
// NEW (round 13): 2 edges per wave-iteration — 32 lanes x uint2 (8 B) cover one
// 256 B x-row, half = lane>>5 selects the edge. Unroll-8: 2x s_load_dwordx4 keys
// + 4 independent row loads = 8 edges in flight (round-12 covered 4 with the same
// MLP). Epilogue: one shfl_xor(32) cross-half add + uint2 store by lanes 0-31.
__global__ void cluster_reduce4(const uint_t* __restrict__ offs2, const uint_t* __restrict__ pkW,
                                const uint_t* __restrict__ xb, uint_t* __restrict__ paggw) {
    int tid = threadIdx.x;
    int lane = tid & 63;
    int half = lane >> 5;
    int l5 = lane & 31;
    int s = blockIdx.x & 7;
    int c = (blockIdx.x >> 3) * 4 + (tid >> 6);     // 0..24999
    uint_t kk = (uint_t)s * CC + (uint_t)c;
    uint_t start = (uint_t)__builtin_amdgcn_readfirstlane((int)offs2[kk]);
    uint_t end   = (uint_t)__builtin_amdgcn_readfirstlane((int)offs2[kk + 1]);
    const uint2* x2 = (const uint2*)xb;             // row = 32 uint2 of 8 B
    float a0 = 0.f, a1 = 0.f, a2 = 0.f, a3 = 0.f;
    uint_t i = start;
    for (; i + 8u <= end; i += 8u) {
        uint_t w0 = pkW[i + 0u], w1 = pkW[i + 1u], w2 = pkW[i + 2u], w3 = pkW[i + 3u];
        uint_t w4 = pkW[i + 4u], w5 = pkW[i + 5u], w6 = pkW[i + 6u], w7 = pkW[i + 7u];
        uint_t sA = (half ? w1 : w0) & 0x1FFFFu;
        uint_t sB = (half ? w3 : w2) & 0x1FFFFu;
        uint_t sC = (half ? w5 : w4) & 0x1FFFFu;
        uint_t sD = (half ? w7 : w6) & 0x1FFFFu;
        uint2 xA = x2[(size_t)sA * 32u + l5];
        uint2 xB = x2[(size_t)sB * 32u + l5];
        uint2 xC = x2[(size_t)sC * 32u + l5];
        uint2 xD = x2[(size_t)sD * 32u + l5];
        a0 += bf2f((ushort_t)(xA.x & 0xffffu)); a1 += bf2f((ushort_t)(xA.x >> 16));
        a2 += bf2f((ushort_t)(xA.y & 0xffffu)); a3 += bf2f((ushort_t)(xA.y >> 16));
        a0 += bf2f((ushort_t)(xB.x & 0xffffu)); a1 += bf2f((ushort_t)(xB.x >> 16));
        a2 += bf2f((ushort_t)(xB.y & 0xffffu)); a3 += bf2f((ushort_t)(xB.y >> 16));
        a0 += bf2f((ushort_t)(xC.x & 0xffffu)); a1 += bf2f((ushort_t)(xC.x >> 16));
        a2 += bf2f((ushort_t)(xC.y & 0xffffu)); a3 += bf2f((ushort_t)(xC.y >> 16));
        a0 += bf2f((ushort_t)(xD.x & 0xffffu)); a1 += bf2f((ushort_t)(xD.x >> 16));
        a2 += bf2f((ushort_t)(xD.y & 0xffffu)); a3 += bf2f((ushort_t)(xD.y >> 16));
    }
    for (; i + 2u <= end; i += 2u) {
        uint_t w0 = pkW[i], w1 = pkW[i + 1u];
        uint_t sA = (half ? w1 : w0) & 0x1FFFFu;
        uint2 xA = x2[(size_t)sA * 32u + l5];
        a0 += bf2f((ushort_t)(xA.x & 0xffffu)); a1 += bf2f((ushort_t)(xA.x >> 16));
        a2 += bf2f((ushort_t)(xA.y & 0xffffu)); a3 += bf2f((ushort_t)(xA.y >> 16));
    }
    if (i < end && half == 0) {
        uint_t sA = pkW[i] & 0x1FFFFu;
        uint2 xA = x2[(size_t)sA * 32u + l5];
        a0 += bf2f((ushort_t)(xA.x & 0xffffu)); a1 += bf2f((ushort_t)(xA.x >> 16));
        a2 += bf2f((ushort_t)(xA.y & 0xffffu)); a3 += bf2f((ushort_t)(xA.y >> 16));
    }
    a0 += __shfl_xor(a0, 32, 64);
    a1 += __shfl_xor(a1, 32, 64);
    a2 += __shfl_xor(a2, 32, 64);
    a3 += __shfl_xor(a3, 32, 64);
    if (half == 0) {
        uint2 r;
        r.x = f2bf(a0) | (f2bf(a1) << 16);
        r.y = f2bf(a2) | (f2bf(a3) << 16);
        *(uint2*)(paggw + (size_t)kk * 66 + 2 * l5) = r;   // words 0..63; 64/65 by sort_A2
    }
}

// K4: x_new[c][o] = 0.25 * sum_{j<131} (sum_s pagg[s][c][j]) * M1[j][o].
// agg_merge fused into the staging loop (slice order s=0..7 preserved).
#define GEMM_CPB 32   // clusters per block = 4 iterations of 8
__global__ void gemm_tiled(const uint_t* __restrict__ paggw, const ushort_t* __restrict__ m1b,
                           float* __restrict__ out) {
    __shared__ ushort_t m1s[131 * 128];            // 33.5 KB bf16
    __shared__ __align__(16) float srowT[132][8];  // 4.2 KB, [j][cluster-in-group]
    int tid = threadIdx.x;
    {
        const uint_t* m1w = (const uint_t*)m1b;
        uint_t* m1sw = (uint_t*)m1s;
        for (int i = tid; i < 131 * 64; i += 256) m1sw[i] = m1w[i];
    }
    int o = tid & 127, half = tid >> 7;
    int c0b = blockIdx.x * GEMM_CPB;
    for (int it = 0; it < GEMM_CPB / 8; ++it) {
        int c0 = c0b + it * 8;
        __syncthreads();   // previous-iteration readers done before overwrite
        for (int i = tid; i < 528; i += 256) {
            int cg = i / 66, rem = i - cg * 66;
            int c = c0 + cg;
            float lo = 0.f, hi = 0.f;
            if (c < CC) {
                #pragma unroll
                for (int s = 0; s < 8; ++s) {
                    uint_t w = paggw[((size_t)s * 25000u + (uint_t)c) * 66 + rem];
                    lo += bf2f((ushort_t)(w & 0xffffu));
                    hi += bf2f((ushort_t)(w >> 16));
                }
            }
            srowT[rem * 2][cg]     = lo;
            srowT[rem * 2 + 1][cg] = hi;
        }
        __syncthreads();   // also covers m1s staging on it==0
        float acc0 = 0.f, acc1 = 0.f, acc2 = 0.f, acc3 = 0.f;
        #pragma unroll 4
        for (int j = 0; j < 131; ++j) {
            float m = bf2f(m1s[j * 128 + o]);
            float4 s = *(const float4*)&srowT[j][half * 4];  // broadcast within wave
            acc0 += s.x * m;
            acc1 += s.y * m;
            acc2 += s.z * m;
            acc3 += s.w * m;
        }
        int cb = c0 + half * 4;
        if (cb + 0 < CC) out[O_XNEW + (size_t)(cb + 0) * 128 + o] = 0.25f * acc0;
        if (cb + 1 < CC) out[O_XNEW + (size_t)(cb + 1) * 128 + o] = 0.25f * acc1;
        if (cb + 2 < CC) out[O_XNEW + (size_t)(cb + 2) * 128 + o] = 0.25f * acc2;
        if (cb + 3 < CC) out[O_XNEW + (size_t)(cb + 3) * 128 + o] = 0.25f * acc3;
    }
}

// K6a: per-segment dedupe: read OWN ~256-entry segment, 12.5 KB LDS bitmap
// (4 u-clusters x 25000 v bits), block scan, emit deduped keys (le, rank-dense)
// to kbuf[bid*KCAP] + count. Bitmap built ONCE (emit kernel reads keys, not pkC).
__global__ void enc_count(const uint_t* __restrict__ csub, const uint_t* __restrict__ pkC,
                          uint_t* __restrict__ bcnt, uint_t* __restrict__ kbuf) {
    __shared__ uint_t bmp[3125];
    __shared__ uint_t sh[256];
    int tid = threadIdx.x, bid = blockIdx.x;
    uint_t s = csub[bid], epos = csub[bid + 1];
    int n = (int)(epos - s);
    for (int i = tid; i < 3125; i += 256) bmp[i] = 0;
    __syncthreads();
    for (int i = tid; i < n; i += 256) {
        uint_t w = pkC[s + i];
        uint_t le = ((w >> 15) & 3u) * 25000u + (w & 32767u);
        atomicOr(&bmp[le >> 5], 1u << (le & 31u));
    }
    __syncthreads();
    int lo = tid * 13, hi = lo + 13;
    if (lo > 3125) lo = 3125;
    if (hi > 3125) hi = 3125;
    uint_t mine = 0;
    for (int i = lo; i < hi; ++i) mine += __popc(bmp[i]);
    sh[tid] = mine;
    __syncthreads();
    for (int off = 1; off < 256; off <<= 1) {
        uint_t v = (tid >= off) ? sh[tid - off] : 0u;
        __syncthreads();
        sh[tid] += v;
        __syncthreads();
    }
    uint_t r = sh[tid] - mine;
    uint_t kb = (uint_t)bid * KCAP;
    for (int i = lo; i < hi; ++i) {
        uint_t bits = bmp[i];
        while (bits) {
            int b = __builtin_ctz(bits);
            bits &= bits - 1u;
            if (r < KCAP) kbuf[kb + r] = (uint_t)i * 32u + (uint_t)b;
            r++;
        }
    }
    if (tid == 255) bcnt[bid] = min(sh[255], (uint_t)KCAP);
}

// K6b: decode dense keys, write u/v COALESCED + attrs (np gathers are L2-resident).
// Global order: bid asc (= u-group asc), key asc within (= (u&3, v) asc) ->
// ascending enc, identical to jnp.unique output order.
__global__ void enc_emit(const uint_t* __restrict__ ebase, const uint_t* __restrict__ kbuf,
                         float* __restrict__ out) {
    int tid = threadIdx.x, bid = blockIdx.x;
    uint_t g0 = ebase[bid], g1 = ebase[bid + 1];
    int cnt = (int)(g1 - g0);
    const float* np = out + O_POS;
    uint_t ubase = ((uint_t)(bid >> 5)) * 128u + ((uint_t)(bid & 31)) * 4u;
    uint_t kb = (uint_t)bid * KCAP;
    for (int r = tid; r < cnt; r += 256) {
        uint_t le = kbuf[kb + r];
        uint_t uo = le / 25000u;
        uint_t v = le - uo * 25000u;
        uint_t u = ubase + uo;
        uint_t rank = g0 + (uint_t)r;
        out[O_EI + rank] = (float)u;
        out[O_EI + EE + rank] = (float)v;
        out[O_ATTR + (size_t)rank * 3 + 0] = np[v * 3 + 0] - np[u * 3 + 0];
        out[O_ATTR + (size_t)rank * 3 + 1] = np[v * 3 + 1] - np[u * 3 + 1];
        out[O_ATTR + (size_t)rank * 3 + 2] = np[v * 3 + 2] - np[u * 3 + 2];
    }
}

extern "C" void kernel_launch(void* const* d_in, const int* in_sizes, int n_in,
                              void* d_out, int out_size, void* d_ws, size_t ws_size,
                              hipStream_t stream) {
    const float* x     = (const float*)d_in[0];
    const float* pos   = (const float*)d_in[1];
    const int*   ei    = (const int*)d_in[2];
    const float* ea    = (const float*)d_in[3];
    const int*   batch = (const int*)d_in[4];
    const float* Wconv = (const float*)d_in[5];
    const float* Wedge = (const float*)d_in[6];
    // d_in[7] = D_bloom: dead (bloom_pos never reaches an output)
    const float* Wg    = (const float*)d_in[8];
    // d_in[9] = W_gattr: contribution cancels exactly within each cluster

    float*  out = (float*)d_out;
    uint_t* ws  = (uint_t*)d_ws;

    if (ws_size < (size_t)WS_WORDS * 4) return;

    ushort_t* m1b    = (ushort_t*)(ws + W_M1B);
    uint_t*   pkW    = ws + W_AGGB;             // sorted keys
    uint_t*   paggw  = ws + W_PAGG;
    uint4*    pk4    = (uint4*)(ws + W_PKA4);
    uint_t*   pkC    = ws + W_PKC;
    uint_t*   offs2  = ws + W_OFFS2;
    uint_t*   bhA2   = ws + W_BHA2;
    uint_t*   bhC    = ws + W_BHC;
    uint_t*   bbA2   = ws + W_BBA2;
    uint_t*   bcurA2 = ws + W_BCURA2;
    uint_t*   bbC    = ws + W_BBC;
    uint_t*   bcurC  = ws + W_BCURC;
    uint_t*   xb     = (uint_t*)(out + O_EI);   // 6.4M-word bf16-x staging in out region
    // dead-region reuse (valid after bucket_sort_A2 / gemm_tiled):
    uint_t*   csub   = ws + W_PKA4;             // u32 [NSEG+1]
    uint_t*   bcnt2  = ws + W_PKA4 + 8192u;     // u32 [NSEG]
    uint_t*   ebase2 = ws + W_PKA4 + 16384u;    // u32 [NSEG+1]
    uint_t*   kbuf   = ws + W_PAGG;             // u32 [NSEG*KCAP] = 6.42M <= 13.2M

    hipMemsetAsync(bhA2, 0, (size_t)(NBKT2 + NBKT) * 4, stream);   // bhA2 + bhC contiguous

    xpack<<<dim3(12500), dim3(256), 0, stream>>>((const float4*)x, (uint2*)xb);
    build_m1f<<<dim3(131), dim3(128), 0, stream>>>(Wconv, Wedge, Wg, m1b);
    edge_hist2<<<dim3(256), dim3(1024), 0, stream>>>(ei, bhA2, bhC);
    scan_small<<<dim3(1), dim3(256), 0, stream>>>(bhA2, bbA2, bcurA2, NBKT2);
    scan_small<<<dim3(1), dim3(256), 0, stream>>>(bhC, bbC, bcurC, NBKT);
    bucket_place_AC<<<dim3((EE + TPB - 1) / TPB), dim3(1024), 0, stream>>>(ei, ea, bcurA2, bcurC, pk4, pkC);
    bucket_sort_A2<<<dim3(NBKT2), dim3(256), 0, stream>>>(bbA2, pk4, pkW, paggw, offs2);
    cluster_pass<<<dim3(98), dim3(256), 0, stream>>>(pos, batch, out);
    cluster_reduce4<<<dim3(50000), dim3(256), 0, stream>>>(offs2, pkW, xb, paggw);
    gemm_tiled<<<dim3((CC + GEMM_CPB - 1) / GEMM_CPB), dim3(256), 0, stream>>>(paggw, m1b, out);
    // x_bf16 staging no longer needed: zero the EI/ATTR region (incl. padding tail)
    hipMemsetAsync((char*)d_out + (size_t)O_EI * 4, 0, (size_t)(3200000 + 4800000) * 4, stream);
    bucket_sort_C<<<dim3(NBKT), dim3(256), 0, stream>>>(bbC, pkC, csub);
    enc_count<<<dim3(NSEG), dim3(256), 0, stream>>>(csub, pkC, bcnt2, kbuf);
    scan_small<<<dim3(1), dim3(256), 0, stream>>>(bcnt2, ebase2, (uint_t*)0, NSEG);
    enc_emit<<<dim3(NSEG), dim3(256), 0, stream>>>(ebase2, kbuf, out);
}

// Round 14
// 423.919 us; speedup vs baseline: 1.1865x; 1.0167x over previous
//
#include <hip/hip_runtime.h>
#include <hip/hip_bf16.h>
#include <stdint.h>

typedef unsigned int uint_t;
typedef unsigned short ushort_t;

#define NN 100000
#define EE 1600000
#define CC 25000
#define DINTER 144
#define NBKT 196          // C-side coarse buckets: src cluster >> 7
#define NBKT2 1568        // A-side buckets: (src_node/12500)*196 + (dst_node>>9)
#define NSEG 6272         // dedupe segments: 196 buckets * 32 subs (4 u-clusters each)
#define KCAP 1024         // keys per segment cap (mean 256, sigma 16 -> +48 sigma)

// ---- ws layout in 32-bit words (total 92.27 MB, proven) ----
#define W_M1B      0u         // u16 [131*128] bf16 m1 = 8384 words
#define W_AGGB     8384u      // pkW sorted keys region (u32 [1,600,000] fits in 1,650,000)
#define W_PAGG     1658384u   // bf16[8][25000*132] = 13,200,000 words (kbuf reuse after gemm)
#define W_PKA4     14858384u  // uint4[1,600,000] = 6,400,000 words (csub/bcnt/ebase reuse after sort)
#define W_PKC      21258384u  // u32 [1600000]
#define W_OFFS2    22858384u  // u32 [200001]  per-(slice,cluster) segment offsets
#define W_BHA2     23058385u  // u32 [1568]
#define W_BHC      23059953u  // u32 [196]   (adjacent to BHA2: one memset of 1764)
#define W_BBA2     23060149u  // u32 [1569]
#define W_BCURA2   23061718u  // u32 [1568]
#define W_BBC      23063286u  // u32 [197]
#define W_BCURC    23063483u  // u32 [196]
#define WS_WORDS   23066816u

// ---- out layout in FLOAT32 elements (total 11,300,000) ----
#define O_XNEW  0u
#define O_POS   3200000u
#define O_EI    3275000u
#define O_ATTR  6475000u
#define O_BATCH 11275000u
// x_bf16 staging: first 6.4M words of the O_EI region (tails zeroed by tail_zero)
// new_pos f32[25000*3] lives at out[O_POS] and is read back by enc_emit.

static __device__ __forceinline__ uint_t f2bf(float f) {
    union { float f; uint_t i; } v; v.f = f;
    uint_t x = v.i;
    return (x + 0x7fffu + ((x >> 16) & 1u)) >> 16;  // RNE
}
static __device__ __forceinline__ float bf2f(ushort_t u) {
    union { uint_t i; float f; } v; v.i = ((uint_t)u) << 16; return v.f;
}

// K0: pack x (f32) -> bf16x2 words into the output-staging region.
__global__ void xpack(const float4* __restrict__ x4, uint2* __restrict__ xb2) {
    int i = blockIdx.x * 256 + threadIdx.x;
    if (i >= NN * 32) return;            // 12.8M floats / 4
    float4 v = x4[i];
    uint2 r;
    r.x = f2bf(v.x) | (f2bf(v.y) << 16);
    r.y = f2bf(v.z) | (f2bf(v.w) << 16);
    xb2[i] = r;
}

// K1: M1[j][o] = sum_f Wrow_j[f] * Wg[f][o], emitted directly as bf16.
__global__ void build_m1f(const float* __restrict__ Wconv,
                          const float* __restrict__ Wedge,
                          const float* __restrict__ Wg,
                          ushort_t* __restrict__ m1b) {
    int j = blockIdx.x;   // 0..130
    int o = threadIdx.x;  // 0..127
    const float* wrow = (j < 128) ? (Wconv + j * DINTER + 16)
                                  : (Wedge + (j - 128) * DINTER + 16);
    float acc = 0.f;
    for (int f = 0; f < 128; ++f)
        acc += wrow[f] * Wg[f * 128 + o];
    m1b[j * 128 + o] = (ushort_t)f2bf(acc);
}

// K2a: fused coarse histograms (LDS-aggregated). 1024-thread blocks.
__global__ void edge_hist2(const int* __restrict__ ei,
                           uint_t* __restrict__ bhA2, uint_t* __restrict__ bhC) {
    __shared__ uint_t hA[NBKT2], hC[NBKT];
    int tid = threadIdx.x;
    for (int i = tid; i < NBKT2; i += 1024) hA[i] = 0;
    for (int i = tid; i < NBKT; i += 1024) hC[i] = 0;
    __syncthreads();
    for (int e = blockIdx.x * 1024 + tid; e < EE; e += 256 * 1024) {
        uint_t u = (uint_t)ei[e];
        uint_t v = (uint_t)ei[EE + e];
        atomicAdd(&hA[(u / 12500u) * 196u + (v >> 9)], 1u);
        atomicAdd(&hC[u >> 9], 1u);
    }
    __syncthreads();
    for (int i = tid; i < NBKT2; i += 1024) if (hA[i]) atomicAdd(&bhA2[i], hA[i]);
    for (int i = tid; i < NBKT; i += 1024)  if (hC[i]) atomicAdd(&bhC[i], hC[i]);
}

// Single-block exclusive scan. out[0..n] (out[n]=total), optional copy out2[0..n-1].
__global__ void scan_small(const uint_t* __restrict__ in, uint_t* __restrict__ out,
                           uint_t* __restrict__ out2, int n) {
    __shared__ uint_t part[256];
    int tid = threadIdx.x;
    int per = (n + 255) >> 8;
    int lo = tid * per;
    int hi = lo + per; if (hi > n) hi = n;
    if (lo > n) lo = n;
    uint_t s = 0;
    for (int i = lo; i < hi; ++i) s += in[i];
    part[tid] = s;
    __syncthreads();
    for (int off = 1; off < 256; off <<= 1) {
        uint_t v = (tid >= off) ? part[tid - off] : 0u;
        __syncthreads();
        part[tid] += v;
        __syncthreads();
    }
    uint_t run = part[tid] - s;
    for (int i = lo; i < hi; ++i) {
        out[i] = run;
        if (out2) out2[i] = run;
        run += in[i];
    }
    if (tid == 255) out[n] = run;
}

#define TPB 4096
// K2b (FUSED): both bucket scatters in one kernel. ei read from HBM ONCE (the
// A-scatter pass re-reads the block's 32 KB ei segment from L2); the A and C
// scatter latency chains interleave in the same waves. LDS 58.8 KB -> 2 blocks/CU.
__global__ void bucket_place_AC(const int* __restrict__ ei, const float* __restrict__ ea,
                                uint_t* __restrict__ bcurA, uint_t* __restrict__ bcurC,
                                uint4* __restrict__ pk4, uint_t* __restrict__ pkC) {
    __shared__ uint_t histA[NBKT2], gbaseA[NBKT2], curA[NBKT2];   // 18.8 KB
    __shared__ uint_t pkst[TPB];                                  // 16 KB C-keys
    __shared__ uint_t gpk[TPB];                                   // 16 KB reordered
    __shared__ uint_t histC[NBKT], lbaseC[NBKT], gbaseC[NBKT], curC[NBKT];
    __shared__ uint_t part[1024];
    int tid = threadIdx.x;
    int t0 = blockIdx.x * TPB;
    int nt = EE - t0; if (nt > TPB) nt = TPB;
    for (int i = tid; i < NBKT2; i += 1024) { histA[i] = 0; curA[i] = 0; }
    for (int i = tid; i < NBKT; i += 1024) { histC[i] = 0; curC[i] = 0; }
    __syncthreads();
    for (int i = tid; i < nt; i += 1024) {
        int e = t0 + i;
        uint_t u = (uint_t)ei[e];
        uint_t v = (uint_t)ei[EE + e];
        atomicAdd(&histA[(u / 12500u) * 196u + (v >> 9)], 1u);
        uint_t w = ((u >> 2) << 15) | (v >> 2);
        pkst[i] = w;
        atomicAdd(&histC[w >> 22], 1u);
    }
    __syncthreads();
    for (int b = tid; b < NBKT2; b += 1024) {
        uint_t h = histA[b];
        if (h) gbaseA[b] = atomicAdd(&bcurA[b], h);
    }
    uint_t h = (tid < NBKT) ? histC[tid] : 0u;
    if (tid < NBKT) gbaseC[tid] = atomicAdd(&bcurC[tid], h);
    part[tid] = h;
    __syncthreads();
    for (int off = 1; off < 1024; off <<= 1) {
        uint_t v = (tid >= off) ? part[tid - off] : 0u;
        __syncthreads();
        part[tid] += v;
        __syncthreads();
    }
    if (tid < NBKT) lbaseC[tid] = part[tid] - h;
    __syncthreads();
    // C-side LDS reorder, then grouped global write
    for (int i = tid; i < nt; i += 1024) {
        uint_t w = pkst[i];
        uint_t b = w >> 22;
        uint_t r = lbaseC[b] + atomicAdd(&curC[b], 1u);
        gpk[r] = w;
    }
    __syncthreads();
    for (int r = tid; r < nt; r += 1024) {
        uint_t w = gpk[r];
        uint_t b = w >> 22;
        pkC[gbaseC[b] + ((uint_t)r - lbaseC[b])] = w;
    }
    // A-side scatter: ei re-read is L2-hot; ea read coalesced once
    for (int i = tid; i < nt; i += 1024) {
        int e = t0 + i;
        uint_t u = (uint_t)ei[e];
        uint_t v = (uint_t)ei[EE + e];
        uint_t b = (u / 12500u) * 196u + (v >> 9);
        uint_t r = gbaseA[b] + atomicAdd(&curA[b], 1u);
        uint4 p;
        p.x = (((v >> 2) & 127u) << 17) | u;
        p.y = __float_as_uint(ea[(size_t)e * 3 + 0]);
        p.z = __float_as_uint(ea[(size_t)e * 3 + 1]);
        p.w = __float_as_uint(ea[(size_t)e * 3 + 2]);
        pk4[r] = p;
    }
}

// K2c: in-LDS counting sort of each (slice, dst-coarse) bucket by cluster-local id;
// sorted KEYS (.x) written to pkW. ea sums per cluster via LDS FLOAT ATOMICS keyed
// by the cluster id in the key (order-independent — round-8's sorted-range read of
// unsorted st[] was the absmax=41.9 bug).
__global__ void bucket_sort_A2(const uint_t* __restrict__ bbA2, const uint4* __restrict__ pk4,
                               uint_t* __restrict__ pkW, uint_t* __restrict__ paggw,
                               uint_t* __restrict__ offs2) {
    __shared__ uint4 st[2048];                      // 32 KB payload staging
    __shared__ uint_t hist[128], base2[128], cur[128];
    __shared__ float eacc0[128], eacc1[128], eacc2[128];
    __shared__ uint_t part[256];
    int tid = threadIdx.x, bk = blockIdx.x;
    uint_t s = bbA2[bk], epos = bbA2[bk + 1];
    int n = (int)(epos - s);
    if (n > 2048) n = 2048;   // statistically unreachable; guards LDS bounds
    if (tid < 128) {
        hist[tid] = 0; cur[tid] = 0;
        eacc0[tid] = 0.f; eacc1[tid] = 0.f; eacc2[tid] = 0.f;
    }
    for (int i = tid; i < n; i += 256) st[i] = pk4[s + i];
    __syncthreads();
    for (int i = tid; i < n; i += 256) {
        uint4 p = st[i];
        uint_t d = p.x >> 17;
        atomicAdd(&hist[d], 1u);
        atomicAdd(&eacc0[d], __uint_as_float(p.y));
        atomicAdd(&eacc1[d], __uint_as_float(p.z));
        atomicAdd(&eacc2[d], __uint_as_float(p.w));
    }
    __syncthreads();
    uint_t h = (tid < 128) ? hist[tid] : 0u;
    part[tid] = h;
    __syncthreads();
    for (int off = 1; off < 256; off <<= 1) {
        uint_t v = (tid >= off) ? part[tid - off] : 0u;
        __syncthreads();
        part[tid] += v;
        __syncthreads();
    }
    int sl = bk / 196, q = bk - sl * 196;
    if (tid < 128) {
        base2[tid] = part[tid] - h;
        int c = q * 128 + tid;
        if (c < CC) {
            uint_t kk = (uint_t)sl * CC + (uint_t)c;
            offs2[kk] = s + base2[tid];
            paggw[(size_t)kk * 66 + 64] = f2bf(eacc0[tid]) | (f2bf(eacc1[tid]) << 16);
            paggw[(size_t)kk * 66 + 65] = f2bf(eacc2[tid]);   // slot 131 = 0
        }
    }
    if (bk == 0 && tid == 0) offs2[8 * CC] = EE;
    __syncthreads();
    for (int i = tid; i < n; i += 256) {
        uint4 p = st[i];
        uint_t d = p.x >> 17;
        uint_t r = base2[d] + atomicAdd(&cur[d], 1u);
        pkW[s + r] = p.x;
    }
}

// K2c': counting-sort each C-bucket by 5-bit sub key ((u>>2)&31), in place, so the
// dedupe kernels read ONLY their own ~256-entry segment.
__global__ void bucket_sort_C(const uint_t* __restrict__ bbC, uint_t* __restrict__ pkC,
                              uint_t* __restrict__ csub) {
    __shared__ uint_t st[8960];                     // 35.8 KB (bucket mean 8192, +8.5 sigma)
    __shared__ uint_t hist[32], base2[32], cur[32];
    __shared__ uint_t part[256];
    int tid = threadIdx.x, bk = blockIdx.x;
    uint_t s = bbC[bk], epos = bbC[bk + 1];
    int n = (int)(epos - s);
    if (n > 8960) n = 8960;
    if (tid < 32) { hist[tid] = 0; cur[tid] = 0; }
    for (int i = tid; i < n; i += 256) st[i] = pkC[s + i];
    __syncthreads();
    for (int i = tid; i < n; i += 256) atomicAdd(&hist[(st[i] >> 17) & 31u], 1u);
    __syncthreads();
    uint_t h = (tid < 32) ? hist[tid] : 0u;
    part[tid] = h;
    __syncthreads();
    for (int off = 1; off < 256; off <<= 1) {
        uint_t v = (tid >= off) ? part[tid - off] : 0u;
        __syncthreads();
        part[tid] += v;
        __syncthreads();
    }
    if (tid < 32) {
        base2[tid] = part[tid] - h;
        csub[bk * 32 + tid] = s + base2[tid];
    }
    if (bk == 0 && tid == 0) csub[NSEG] = EE;
    __syncthreads();
    for (int i = tid; i < n; i += 256) {
        uint_t w = st[i];
        uint_t d = (w >> 17) & 31u;
        uint_t r = base2[d] + atomicAdd(&cur[d], 1u);
        pkC[s + r] = w;
    }
}

// K3: per cluster: new_pos + new_batch straight to out (enc_emit reads out[O_POS]).
__global__ void cluster_pass(const float* __restrict__ pos, const int* __restrict__ batch,
                             float* __restrict__ out) {
    int c = blockIdx.x * 256 + threadIdx.x;
    if (c >= CC) return;
    float px = 0.f, py = 0.f, pz = 0.f;
    for (int j = 0; j < 4; ++j) {
        int n = c * 4 + j;
        px += pos[n * 3 + 0];
        py += pos[n * 3 + 1];
        pz += pos[n * 3 + 2];
    }
    px *= 0.25f; py *= 0.25f; pz *= 0.25f;
    out[O_POS + c * 3 + 0] = px;
    out[O_POS + c * 3 + 1] = py;
    out[O_POS + c * 3 + 2] = pz;
    int b = batch[c * 4];
    b = max(b, batch[c * 4 + 1]);
    b = max(b, batch[c * 4 + 2]);
    b = max(b, batch[c * 4 + 3]);
    out[O_BATCH + c] = (float)b;
}

// K2d (round 14): 8 clusters per WAVE. Round-13 post-mortem: 200K waves x ~600 cy
// fixed overhead (scalar bound loads + setup + store + drain) ~= the whole 50 us —
// the edge loop was never the bound. One wave now walks 8 consecutive clusters of
// its slice (one contiguous pkW range, bounds = 9 adjacent offs2 words -> scalar
// cache hits), amortizing the overhead 8x. Inner loop = verified round-12 unroll-4
// (bit-identical per-cluster accumulation). Empty clusters still write zero rows.
#define CPW 8
__global__ void cluster_reduce5(const uint_t* __restrict__ offs2, const uint_t* __restrict__ pkW,
                                const uint_t* __restrict__ xb, uint_t* __restrict__ paggw) {
    int tid = threadIdx.x;
    int lane = tid & 63;
    int s = blockIdx.x & 7;
    int c0 = ((blockIdx.x >> 3) * 4 + (tid >> 6)) * CPW;   // 4 waves/block
    if (c0 >= CC) return;
    uint_t kk0 = (uint_t)s * CC + (uint_t)c0;
    const uint_t* xl = xb + lane;
    for (int cl = 0; cl < CPW; ++cl) {
        if (c0 + cl >= CC) break;
        uint_t start = (uint_t)__builtin_amdgcn_readfirstlane((int)offs2[kk0 + cl]);
        uint_t end   = (uint_t)__builtin_amdgcn_readfirstlane((int)offs2[kk0 + cl + 1]);
        float a0 = 0.f, a1 = 0.f;
        uint_t i = start;
        for (; i + 4u <= end; i += 4u) {
            uint_t w0 = pkW[i + 0u];                // uniform, consecutive -> s_load_dwordx4
            uint_t w1 = pkW[i + 1u];
            uint_t w2 = pkW[i + 2u];
            uint_t w3 = pkW[i + 3u];
            uint_t x0 = xl[(size_t)(w0 & 0x1FFFFu) * 64u];   // 4 independent 256 B row loads
            uint_t x1 = xl[(size_t)(w1 & 0x1FFFFu) * 64u];
            uint_t x2 = xl[(size_t)(w2 & 0x1FFFFu) * 64u];
            uint_t x3 = xl[(size_t)(w3 & 0x1FFFFu) * 64u];
            a0 += bf2f((ushort_t)(x0 & 0xffffu)); a1 += bf2f((ushort_t)(x0 >> 16));
            a0 += bf2f((ushort_t)(x1 & 0xffffu)); a1 += bf2f((ushort_t)(x1 >> 16));
            a0 += bf2f((ushort_t)(x2 & 0xffffu)); a1 += bf2f((ushort_t)(x2 >> 16));
            a0 += bf2f((ushort_t)(x3 & 0xffffu)); a1 += bf2f((ushort_t)(x3 >> 16));
        }
        for (; i < end; ++i) {
            uint_t wj = pkW[i];
            uint_t xv = xl[(size_t)(wj & 0x1FFFFu) * 64u];
            a0 += bf2f((ushort_t)(xv & 0xffffu));
            a1 += bf2f((ushort_t)(xv >> 16));
        }
        paggw[(size_t)(kk0 + (uint_t)cl) * 66 + lane] = f2bf(a0) | (f2bf(a1) << 16);
    }
}

// K4: x_new[c][o] = 0.25 * sum_{j<131} (sum_s pagg[s][c][j]) * M1[j][o].
// agg_merge fused into the staging loop (slice order s=0..7 preserved).
#define GEMM_CPB 32   // clusters per block = 4 iterations of 8
__global__ void gemm_tiled(const uint_t* __restrict__ paggw, const ushort_t* __restrict__ m1b,
                           float* __restrict__ out) {
    __shared__ ushort_t m1s[131 * 128];            // 33.5 KB bf16
    __shared__ __align__(16) float srowT[132][8];  // 4.2 KB, [j][cluster-in-group]
    int tid = threadIdx.x;
    {
        const uint_t* m1w = (const uint_t*)m1b;
        uint_t* m1sw = (uint_t*)m1s;
        for (int i = tid; i < 131 * 64; i += 256) m1sw[i] = m1w[i];
    }
    int o = tid & 127, half = tid >> 7;
    int c0b = blockIdx.x * GEMM_CPB;
    for (int it = 0; it < GEMM_CPB / 8; ++it) {
        int c0 = c0b + it * 8;
        __syncthreads();   // previous-iteration readers done before overwrite
        for (int i = tid; i < 528; i += 256) {
            int cg = i / 66, rem = i - cg * 66;
            int c = c0 + cg;
            float lo = 0.f, hi = 0.f;
            if (c < CC) {
                #pragma unroll
                for (int s = 0; s < 8; ++s) {
                    uint_t w = paggw[((size_t)s * 25000u + (uint_t)c) * 66 + rem];
                    lo += bf2f((ushort_t)(w & 0xffffu));
                    hi += bf2f((ushort_t)(w >> 16));
                }
            }
            srowT[rem * 2][cg]     = lo;
            srowT[rem * 2 + 1][cg] = hi;
        }
        __syncthreads();   // also covers m1s staging on it==0
        float acc0 = 0.f, acc1 = 0.f, acc2 = 0.f, acc3 = 0.f;
        #pragma unroll 4
        for (int j = 0; j < 131; ++j) {
            float m = bf2f(m1s[j * 128 + o]);
            float4 s = *(const float4*)&srowT[j][half * 4];  // broadcast within wave
            acc0 += s.x * m;
            acc1 += s.y * m;
            acc2 += s.z * m;
            acc3 += s.w * m;
        }
        int cb = c0 + half * 4;
        if (cb + 0 < CC) out[O_XNEW + (size_t)(cb + 0) * 128 + o] = 0.25f * acc0;
        if (cb + 1 < CC) out[O_XNEW + (size_t)(cb + 1) * 128 + o] = 0.25f * acc1;
        if (cb + 2 < CC) out[O_XNEW + (size_t)(cb + 2) * 128 + o] = 0.25f * acc2;
        if (cb + 3 < CC) out[O_XNEW + (size_t)(cb + 3) * 128 + o] = 0.25f * acc3;
    }
}

// K6a: per-segment dedupe: read OWN ~256-entry segment, 12.5 KB LDS bitmap
// (4 u-clusters x 25000 v bits), block scan, emit deduped keys (le, rank-dense)
// to kbuf[bid*KCAP] + count. Bitmap built ONCE (emit kernel reads keys, not pkC).
__global__ void enc_count(const uint_t* __restrict__ csub, const uint_t* __restrict__ pkC,
                          uint_t* __restrict__ bcnt, uint_t* __restrict__ kbuf) {
    __shared__ uint_t bmp[3125];
    __shared__ uint_t sh[256];
    int tid = threadIdx.x, bid = blockIdx.x;
    uint_t s = csub[bid], epos = csub[bid + 1];
    int n = (int)(epos - s);
    for (int i = tid; i < 3125; i += 256) bmp[i] = 0;
    __syncthreads();
    for (int i = tid; i < n; i += 256) {
        uint_t w = pkC[s + i];
        uint_t le = ((w >> 15) & 3u) * 25000u + (w & 32767u);
        atomicOr(&bmp[le >> 5], 1u << (le & 31u));
    }
    __syncthreads();
    int lo = tid * 13, hi = lo + 13;
    if (lo > 3125) lo = 3125;
    if (hi > 3125) hi = 3125;
    uint_t mine = 0;
    for (int i = lo; i < hi; ++i) mine += __popc(bmp[i]);
    sh[tid] = mine;
    __syncthreads();
    for (int off = 1; off < 256; off <<= 1) {
        uint_t v = (tid >= off) ? sh[tid - off] : 0u;
        __syncthreads();
        sh[tid] += v;
        __syncthreads();
    }
    uint_t r = sh[tid] - mine;
    uint_t kb = (uint_t)bid * KCAP;
    for (int i = lo; i < hi; ++i) {
        uint_t bits = bmp[i];
        while (bits) {
            int b = __builtin_ctz(bits);
            bits &= bits - 1u;
            if (r < KCAP) kbuf[kb + r] = (uint_t)i * 32u + (uint_t)b;
            r++;
        }
    }
    if (tid == 255) bcnt[bid] = min(sh[255], (uint_t)KCAP);
}

// K6t: zero only the unwritten tails of EI/ATTR (replaces the 32 MB memset; emit
// covers ranks [0,total) which is ~99.7% of the region — the memset was wasted).
__global__ void tail_zero(const uint_t* __restrict__ ebase, float* __restrict__ out) {
    uint_t total = ebase[NSEG];
    uint_t idx = blockIdx.x * 256u + (uint_t)threadIdx.x;
    uint_t stride = gridDim.x * 256u;
    for (uint_t k = total + idx; k < EE; k += stride) {
        out[O_EI + k] = 0.f;
        out[O_EI + EE + k] = 0.f;
    }
    for (uint_t k = 3u * total + idx; k < 3u * EE; k += stride) {
        out[O_ATTR + k] = 0.f;
    }
}

// K6b: decode dense keys, write u/v COALESCED + attrs (np gathers are L2-resident).
// Global order: bid asc (= u-group asc), key asc within (= (u&3, v) asc) ->
// ascending enc, identical to jnp.unique output order.
__global__ void enc_emit(const uint_t* __restrict__ ebase, const uint_t* __restrict__ kbuf,
                         float* __restrict__ out) {
    int tid = threadIdx.x, bid = blockIdx.x;
    uint_t g0 = ebase[bid], g1 = ebase[bid + 1];
    int cnt = (int)(g1 - g0);
    const float* np = out + O_POS;
    uint_t ubase = ((uint_t)(bid >> 5)) * 128u + ((uint_t)(bid & 31)) * 4u;
    uint_t kb = (uint_t)bid * KCAP;
    for (int r = tid; r < cnt; r += 256) {
        uint_t le = kbuf[kb + r];
        uint_t uo = le / 25000u;
        uint_t v = le - uo * 25000u;
        uint_t u = ubase + uo;
        uint_t rank = g0 + (uint_t)r;
        out[O_EI + rank] = (float)u;
        out[O_EI + EE + rank] = (float)v;
        out[O_ATTR + (size_t)rank * 3 + 0] = np[v * 3 + 0] - np[u * 3 + 0];
        out[O_ATTR + (size_t)rank * 3 + 1] = np[v * 3 + 1] - np[u * 3 + 1];
        out[O_ATTR + (size_t)rank * 3 + 2] = np[v * 3 + 2] - np[u * 3 + 2];
    }
}

extern "C" void kernel_launch(void* const* d_in, const int* in_sizes, int n_in,
                              void* d_out, int out_size, void* d_ws, size_t ws_size,
                              hipStream_t stream) {
    const float* x     = (const float*)d_in[0];
    const float* pos   = (const float*)d_in[1];
    const int*   ei    = (const int*)d_in[2];
    const float* ea    = (const float*)d_in[3];
    const int*   batch = (const int*)d_in[4];
    const float* Wconv = (const float*)d_in[5];
    const float* Wedge = (const float*)d_in[6];
    // d_in[7] = D_bloom: dead (bloom_pos never reaches an output)
    const float* Wg    = (const float*)d_in[8];
    // d_in[9] = W_gattr: contribution cancels exactly within each cluster

    float*  out = (float*)d_out;
    uint_t* ws  = (uint_t*)d_ws;

    if (ws_size < (size_t)WS_WORDS * 4) return;

    ushort_t* m1b    = (ushort_t*)(ws + W_M1B);
    uint_t*   pkW    = ws + W_AGGB;             // sorted keys
    uint_t*   paggw  = ws + W_PAGG;
    uint4*    pk4    = (uint4*)(ws + W_PKA4);
    uint_t*   pkC    = ws + W_PKC;
    uint_t*   offs2  = ws + W_OFFS2;
    uint_t*   bhA2   = ws + W_BHA2;
    uint_t*   bhC    = ws + W_BHC;
    uint_t*   bbA2   = ws + W_BBA2;
    uint_t*   bcurA2 = ws + W_BCURA2;
    uint_t*   bbC    = ws + W_BBC;
    uint_t*   bcurC  = ws + W_BCURC;
    uint_t*   xb     = (uint_t*)(out + O_EI);   // 6.4M-word bf16-x staging in out region
    // dead-region reuse (valid after bucket_sort_A2 / gemm_tiled):
    uint_t*   csub   = ws + W_PKA4;             // u32 [NSEG+1]
    uint_t*   bcnt2  = ws + W_PKA4 + 8192u;     // u32 [NSEG]
    uint_t*   ebase2 = ws + W_PKA4 + 16384u;    // u32 [NSEG+1]
    uint_t*   kbuf   = ws + W_PAGG;             // u32 [NSEG*KCAP] = 6.42M <= 13.2M

    hipMemsetAsync(bhA2, 0, (size_t)(NBKT2 + NBKT) * 4, stream);   // bhA2 + bhC contiguous

    xpack<<<dim3(12500), dim3(256), 0, stream>>>((const float4*)x, (uint2*)xb);
    build_m1f<<<dim3(131), dim3(128), 0, stream>>>(Wconv, Wedge, Wg, m1b);
    edge_hist2<<<dim3(256), dim3(1024), 0, stream>>>(ei, bhA2, bhC);
    scan_small<<<dim3(1), dim3(256), 0, stream>>>(bhA2, bbA2, bcurA2, NBKT2);
    scan_small<<<dim3(1), dim3(256), 0, stream>>>(bhC, bbC, bcurC, NBKT);
    bucket_place_AC<<<dim3((EE + TPB - 1) / TPB), dim3(1024), 0, stream>>>(ei, ea, bcurA2, bcurC, pk4, pkC);
    bucket_sort_A2<<<dim3(NBKT2), dim3(256), 0, stream>>>(bbA2, pk4, pkW, paggw, offs2);
    cluster_pass<<<dim3(98), dim3(256), 0, stream>>>(pos, batch, out);
    cluster_reduce5<<<dim3(((CC + 4 * CPW - 1) / (4 * CPW)) * 8), dim3(256), 0, stream>>>(offs2, pkW, xb, paggw);
    gemm_tiled<<<dim3((CC + GEMM_CPB - 1) / GEMM_CPB), dim3(256), 0, stream>>>(paggw, m1b, out);
    bucket_sort_C<<<dim3(NBKT), dim3(256), 0, stream>>>(bbC, pkC, csub);
    enc_count<<<dim3(NSEG), dim3(256), 0, stream>>>(csub, pkC, bcnt2, kbuf);
    scan_small<<<dim3(1), dim3(256), 0, stream>>>(bcnt2, ebase2, (uint_t*)0, NSEG);
    tail_zero<<<dim3(512), dim3(256), 0, stream>>>(ebase2, out);
    enc_emit<<<dim3(NSEG), dim3(256), 0, stream>>>(ebase2, kbuf, out);
}